// Round 2
// baseline (702.186 us; speedup 1.0000x reference)
//
#include <hip/hip_runtime.h>
#include <hip/hip_bf16.h>
#include <cstdio>

#define NB 2
#define NN 4096
#define NC 64
#define NQ 16
#define POS_COEF 0.1f

// ---- workspace layout (float offsets) ----
#define OFF_QT   0u            // [B][N][16]  q transposed
#define OFF_XYZ4 131072u       // [B][N][4]   x,y,z,sq
#define OFF_XVT  163840u       // [B][N][64]  xv transposed
#define OFF_RM1  688128u       // [B][N] row max of corr
#define OFF_RS1  696320u       // [B][N] row sum exp
#define OFF_RM2  704512u       // [B][N] row max of local0
#define OFF_RS2  712704u       // [B][N] row sum exp local
#define OFF_FLAG 720896u       // [16] dtype flag (1.0 = f32 inputs)
#define OFF_CS1  720912u       // [B][N] col sum of softmax     (zeroed)
#define OFF_CSD  729104u       // [B][N] col sum of d           (zeroed)
#define OFF_CS2  737296u       // [B][N] col sum of local-sm    (zeroed)
#define OFF_GN   745488u       // [2][B][8] group sums          (zeroed)
#define OFF_GMA  745520u       // [B][N][64] gma acc, becomes res in k8 (zeroed)
#define WS_TOTAL 1269808u
#define ZERO_F   (WS_TOTAL - OFF_CS1)

__device__ __forceinline__ float b2f(__hip_bfloat16 x) { return __bfloat162float(x); }
__device__ __forceinline__ float rcpf_(float x) { return __builtin_amdgcn_rcpf(x); }

// dtype-agnostic input load (flag is wave-uniform)
__device__ __forceinline__ float ldin(const void* p, size_t i, bool f32) {
  return f32 ? ((const float*)p)[i]
             : __bfloat162float(((const __hip_bfloat16*)p)[i]);
}

__device__ __forceinline__ float dot16(const float4& a, const float4& b,
                                       const float4& c, const float4& d,
                                       const float* __restrict__ w) {
  float s = a.x * w[0];
  s = fmaf(a.y, w[1], s);  s = fmaf(a.z, w[2], s);  s = fmaf(a.w, w[3], s);
  s = fmaf(b.x, w[4], s);  s = fmaf(b.y, w[5], s);  s = fmaf(b.z, w[6], s);  s = fmaf(b.w, w[7], s);
  s = fmaf(c.x, w[8], s);  s = fmaf(c.y, w[9], s);  s = fmaf(c.z, w[10], s); s = fmaf(c.w, w[11], s);
  s = fmaf(d.x, w[12], s); s = fmaf(d.y, w[13], s); s = fmaf(d.z, w[14], s); s = fmaf(d.w, w[15], s);
  return s;
}

// K0: detect input dtype. If ctx is f32 data read as bf16, even-indexed u16s
// are float mantissa halves -> random exponent field -> ~43% implausible.
// True bf16 N(0,1) data -> ~0 implausible.
__global__ __launch_bounds__(256) void k0_detect(
    const unsigned short* __restrict__ ctx_u16, float* __restrict__ flag) {
  const int tid = threadIdx.x;
  int bad = 0;
  for (int i = tid; i < 8192; i += 256) {
    const unsigned short u = ctx_u16[i];
    const int e = (u >> 7) & 0xFF;                    // bf16 exponent field
    if (e >= 134 || (e >= 1 && e <= 100)) bad++;      // |x|>=256 or 0<|x|<2^-26
  }
  __shared__ int cnt;
  if (tid == 0) cnt = 0;
  __syncthreads();
  atomicAdd(&cnt, bad);
  __syncthreads();
  if (tid == 0) flag[0] = (cnt > 256) ? 1.0f : 0.0f;
}

// K1: q = Wqk @ ctx (stored [b][n][16]), xyz4 = {x,y,z,|p|^2}
__global__ __launch_bounds__(256) void k1_q_xyz(
    const void* __restrict__ ctx, const void* __restrict__ xyz,
    const void* __restrict__ wqk, const float* __restrict__ flag,
    float* __restrict__ qt, float* __restrict__ xyz4) {
  const bool f32 = flag[0] > 0.5f;
  const int tid = threadIdx.x;
  const int b = blockIdx.x >> 4;
  const int n = ((blockIdx.x & 15) << 8) + tid;
  __shared__ float wqT[NQ * NC];  // [c][o]
  for (int i = tid; i < NQ * NC; i += 256) {
    int o = i & 15, c = i >> 4;
    wqT[c * 16 + o] = ldin(wqk, o * 64 + c, f32);
  }
  __syncthreads();
  float4 a0 = {0,0,0,0}, a1 = {0,0,0,0}, a2 = {0,0,0,0}, a3 = {0,0,0,0};
  const size_t cbase = (size_t)b * 64 * NN + n;
#pragma unroll 4
  for (int c = 0; c < 64; ++c) {
    float x = ldin(ctx, cbase + (size_t)c * NN, f32);
    const float4 w0 = *(const float4*)(wqT + c * 16 + 0);
    const float4 w1 = *(const float4*)(wqT + c * 16 + 4);
    const float4 w2 = *(const float4*)(wqT + c * 16 + 8);
    const float4 w3 = *(const float4*)(wqT + c * 16 + 12);
    a0.x = fmaf(w0.x, x, a0.x); a0.y = fmaf(w0.y, x, a0.y); a0.z = fmaf(w0.z, x, a0.z); a0.w = fmaf(w0.w, x, a0.w);
    a1.x = fmaf(w1.x, x, a1.x); a1.y = fmaf(w1.y, x, a1.y); a1.z = fmaf(w1.z, x, a1.z); a1.w = fmaf(w1.w, x, a1.w);
    a2.x = fmaf(w2.x, x, a2.x); a2.y = fmaf(w2.y, x, a2.y); a2.z = fmaf(w2.z, x, a2.z); a2.w = fmaf(w2.w, x, a2.w);
    a3.x = fmaf(w3.x, x, a3.x); a3.y = fmaf(w3.y, x, a3.y); a3.z = fmaf(w3.z, x, a3.z); a3.w = fmaf(w3.w, x, a3.w);
  }
  float* qp = qt + (size_t)(b * NN + n) * 16;
  *(float4*)(qp + 0) = a0; *(float4*)(qp + 4) = a1;
  *(float4*)(qp + 8) = a2; *(float4*)(qp + 12) = a3;
  float xx = ldin(xyz, (size_t)(b * NN + n) * 3 + 0, f32);
  float yy = ldin(xyz, (size_t)(b * NN + n) * 3 + 1, f32);
  float zz = ldin(xyz, (size_t)(b * NN + n) * 3 + 2, f32);
  float4 p; p.x = xx; p.y = yy; p.z = zz; p.w = fmaf(xx, xx, fmaf(yy, yy, zz * zz));
  *(float4*)(xyz4 + (size_t)(b * NN + n) * 4) = p;
}

// K2: xv = Wv @ motion + bv  (stored [b][n][64])
__global__ __launch_bounds__(256) void k2_xv(
    const void* __restrict__ mot, const void* __restrict__ wv,
    const void* __restrict__ bv, const float* __restrict__ flag,
    float* __restrict__ xvt) {
  const bool f32 = flag[0] > 0.5f;
  const int tid = threadIdx.x;
  const int b = blockIdx.x >> 6;
  const int n = ((blockIdx.x & 63) << 6) + (tid >> 2);
  const int og = tid & 3;
  __shared__ float wvT[NC * NC];  // [c][o]
  __shared__ float bvs[NC];
  for (int i = tid; i < NC * NC; i += 256) {
    int o = i & 63, c = i >> 6;
    wvT[c * 64 + o] = ldin(wv, o * 64 + c, f32);
  }
  if (tid < 64) bvs[tid] = ldin(bv, tid, f32);
  __syncthreads();
  float4 a0 = *(const float4*)(bvs + og * 16 + 0);
  float4 a1 = *(const float4*)(bvs + og * 16 + 4);
  float4 a2 = *(const float4*)(bvs + og * 16 + 8);
  float4 a3 = *(const float4*)(bvs + og * 16 + 12);
  const size_t mbase = (size_t)b * 64 * NN + n;
#pragma unroll 4
  for (int c = 0; c < 64; ++c) {
    float x = ldin(mot, mbase + (size_t)c * NN, f32);
    const float4 w0 = *(const float4*)(wvT + c * 64 + og * 16 + 0);
    const float4 w1 = *(const float4*)(wvT + c * 64 + og * 16 + 4);
    const float4 w2 = *(const float4*)(wvT + c * 64 + og * 16 + 8);
    const float4 w3 = *(const float4*)(wvT + c * 64 + og * 16 + 12);
    a0.x = fmaf(w0.x, x, a0.x); a0.y = fmaf(w0.y, x, a0.y); a0.z = fmaf(w0.z, x, a0.z); a0.w = fmaf(w0.w, x, a0.w);
    a1.x = fmaf(w1.x, x, a1.x); a1.y = fmaf(w1.y, x, a1.y); a1.z = fmaf(w1.z, x, a1.z); a1.w = fmaf(w1.w, x, a1.w);
    a2.x = fmaf(w2.x, x, a2.x); a2.y = fmaf(w2.y, x, a2.y); a2.z = fmaf(w2.z, x, a2.z); a2.w = fmaf(w2.w, x, a2.w);
    a3.x = fmaf(w3.x, x, a3.x); a3.y = fmaf(w3.y, x, a3.y); a3.z = fmaf(w3.z, x, a3.z); a3.w = fmaf(w3.w, x, a3.w);
  }
  float* dst = xvt + (size_t)(b * NN + n) * 64 + og * 16;
  *(float4*)(dst + 0) = a0; *(float4*)(dst + 4) = a1;
  *(float4*)(dst + 8) = a2; *(float4*)(dst + 12) = a3;
}

// merge helper for online softmax reductions
#define MS_MERGE(m, s, om, os) { float nm_ = fmaxf(m, om); \
  s = s * __expf(m - nm_) + (os) * __expf((om) - nm_); m = nm_; }

// K3: row max / row sum-exp of corr (16 rows per block)
__global__ __launch_bounds__(256) void k3_rowstats1(
    const float* __restrict__ qt, float* __restrict__ rm1, float* __restrict__ rs1) {
  const int tid = threadIdx.x;
  const int b = blockIdx.x >> 8;
  const int m0 = (blockIdx.x & 255) << 4;
  const float* qb = qt + (size_t)b * NN * 16;
  float rmax[16], rsum[16];
#pragma unroll
  for (int i = 0; i < 16; ++i) { rmax[i] = -INFINITY; rsum[i] = 0.f; }
  for (int j = 0; j < 16; ++j) {
    const int n = (j << 8) + tid;
    const float* qn = qb + (size_t)n * 16;
    const float4 q0 = *(const float4*)(qn + 0);
    const float4 q1 = *(const float4*)(qn + 4);
    const float4 q2 = *(const float4*)(qn + 8);
    const float4 q3 = *(const float4*)(qn + 12);
#pragma unroll
    for (int mi = 0; mi < 16; ++mi) {
      const float* qm = qb + (size_t)(m0 + mi) * 16;
      float corr = dot16(q0, q1, q2, q3, qm);
      float mo = rmax[mi];
      float mn = fmaxf(mo, corr);
      rsum[mi] = fmaf(rsum[mi], __expf(mo - mn), __expf(corr - mn));
      rmax[mi] = mn;
    }
  }
  const int lane = tid & 63, wid = tid >> 6;
  __shared__ float pmx[16][4], psm[16][4];
#pragma unroll
  for (int mi = 0; mi < 16; ++mi) {
    float m = rmax[mi], s = rsum[mi];
#pragma unroll
    for (int off = 32; off >= 1; off >>= 1) {
      float om = __shfl_xor(m, off);
      float os = __shfl_xor(s, off);
      MS_MERGE(m, s, om, os);
    }
    if (lane == 0) { pmx[mi][wid] = m; psm[mi][wid] = s; }
  }
  __syncthreads();
  if (tid < 16) {
    float m = pmx[tid][0], s = psm[tid][0];
#pragma unroll
    for (int w = 1; w < 4; ++w) MS_MERGE(m, s, pmx[tid][w], psm[tid][w]);
    rm1[b * NN + m0 + tid] = m;
    rs1[b * NN + m0 + tid] = s;
  }
}

// K4: colsum of softmax(corr) and colsum of d (atomic accumulate)
__global__ __launch_bounds__(256) void k4_colsum1(
    const float* __restrict__ qt, const float* __restrict__ xyz4,
    const float* __restrict__ rm1, const float* __restrict__ rs1,
    float* __restrict__ cs1, float* __restrict__ csd) {
  const int tid = threadIdx.x;
  const int bid = blockIdx.x;
  const int mb = bid & 15, nbk = (bid >> 4) & 15, b = bid >> 8;
  const int n = (nbk << 8) + tid;
  const int m0 = mb << 8;
  const float* qb = qt + (size_t)b * NN * 16;
  const float* pb = xyz4 + (size_t)b * NN * 4;
  const float* qn = qb + (size_t)n * 16;
  const float4 q0 = *(const float4*)(qn + 0);
  const float4 q1 = *(const float4*)(qn + 4);
  const float4 q2 = *(const float4*)(qn + 8);
  const float4 q3 = *(const float4*)(qn + 12);
  const float4 pn = *(const float4*)(pb + (size_t)n * 4);
  float accs = 0.f, accd = 0.f;
#pragma unroll 4
  for (int ml = 0; ml < 256; ++ml) {
    const int m = m0 + ml;
    const float* qm = qb + (size_t)m * 16;
    float corr = dot16(q0, q1, q2, q3, qm);
    accs = fmaf(__expf(corr - rm1[b * NN + m]), rcpf_(rs1[b * NN + m]), accs);
    const float4 pm = *(const float4*)(pb + (size_t)m * 4);
    float dd = pm.w + pn.w - 2.f * (pm.x * pn.x + pm.y * pn.y + pm.z * pn.z);
    accd += fmaxf(dd, 0.f);
  }
  atomicAdd(&cs1[b * NN + n], accs);
  atomicAdd(&csd[b * NN + n], accd);
}

// K5: row max / sum-exp of local0 = attn1 * mask (16 rows per block)
__global__ __launch_bounds__(256) void k5_rowstats2(
    const float* __restrict__ qt, const float* __restrict__ xyz4,
    const float* __restrict__ rm1, const float* __restrict__ rs1,
    const float* __restrict__ cs1, const float* __restrict__ csd,
    float* __restrict__ rm2, float* __restrict__ rs2) {
  const int tid = threadIdx.x;
  const int b = blockIdx.x >> 8;
  const int m0 = (blockIdx.x & 255) << 4;
  const float* qb = qt + (size_t)b * NN * 16;
  const float* pb = xyz4 + (size_t)b * NN * 4;
  float rmax[16], rsum[16];
#pragma unroll
  for (int i = 0; i < 16; ++i) { rmax[i] = -INFINITY; rsum[i] = 0.f; }
  for (int j = 0; j < 16; ++j) {
    const int n = (j << 8) + tid;
    const float* qn = qb + (size_t)n * 16;
    const float4 q0 = *(const float4*)(qn + 0);
    const float4 q1 = *(const float4*)(qn + 4);
    const float4 q2 = *(const float4*)(qn + 8);
    const float4 q3 = *(const float4*)(qn + 12);
    const float4 pn = *(const float4*)(pb + (size_t)n * 4);
    const float ics1 = rcpf_(1e-9f + cs1[b * NN + n]);
    const float icsd = rcpf_(1e-9f + csd[b * NN + n]);
#pragma unroll
    for (int mi = 0; mi < 16; ++mi) {
      const int m = m0 + mi;
      const float* qm = qb + (size_t)m * 16;
      float corr = dot16(q0, q1, q2, q3, qm);
      float a1v = __expf(corr - rm1[b * NN + m]) * rcpf_(rs1[b * NN + m]) * ics1;
      const float4 pm = *(const float4*)(pb + (size_t)m * 4);
      float dd = pm.w + pn.w - 2.f * (pm.x * pn.x + pm.y * pn.y + pm.z * pn.z);
      dd = fmaxf(dd, 0.f);
      float l0 = (dd * icsd <= POS_COEF) ? a1v : 0.f;
      float mo = rmax[mi];
      float mn = fmaxf(mo, l0);
      rsum[mi] = fmaf(rsum[mi], __expf(mo - mn), __expf(l0 - mn));
      rmax[mi] = mn;
    }
  }
  const int lane = tid & 63, wid = tid >> 6;
  __shared__ float pmx[16][4], psm[16][4];
#pragma unroll
  for (int mi = 0; mi < 16; ++mi) {
    float m = rmax[mi], s = rsum[mi];
#pragma unroll
    for (int off = 32; off >= 1; off >>= 1) {
      float om = __shfl_xor(m, off);
      float os = __shfl_xor(s, off);
      MS_MERGE(m, s, om, os);
    }
    if (lane == 0) { pmx[mi][wid] = m; psm[mi][wid] = s; }
  }
  __syncthreads();
  if (tid < 16) {
    float m = pmx[tid][0], s = psm[tid][0];
#pragma unroll
    for (int w = 1; w < 4; ++w) MS_MERGE(m, s, pmx[tid][w], psm[tid][w]);
    rm2[b * NN + m0 + tid] = m;
    rs2[b * NN + m0 + tid] = s;
  }
}

// K6: colsum of softmax(local0)
__global__ __launch_bounds__(256) void k6_colsum2(
    const float* __restrict__ qt, const float* __restrict__ xyz4,
    const float* __restrict__ rm1, const float* __restrict__ rs1,
    const float* __restrict__ rm2, const float* __restrict__ rs2,
    const float* __restrict__ cs1, const float* __restrict__ csd,
    float* __restrict__ cs2) {
  const int tid = threadIdx.x;
  const int bid = blockIdx.x;
  const int mb = bid & 15, nbk = (bid >> 4) & 15, b = bid >> 8;
  const int n = (nbk << 8) + tid;
  const int m0 = mb << 8;
  const float* qb = qt + (size_t)b * NN * 16;
  const float* pb = xyz4 + (size_t)b * NN * 4;
  const float* qn = qb + (size_t)n * 16;
  const float4 q0 = *(const float4*)(qn + 0);
  const float4 q1 = *(const float4*)(qn + 4);
  const float4 q2 = *(const float4*)(qn + 8);
  const float4 q3 = *(const float4*)(qn + 12);
  const float4 pn = *(const float4*)(pb + (size_t)n * 4);
  const float ics1 = rcpf_(1e-9f + cs1[b * NN + n]);
  const float icsd = rcpf_(1e-9f + csd[b * NN + n]);
  float acc = 0.f;
#pragma unroll 4
  for (int ml = 0; ml < 256; ++ml) {
    const int m = m0 + ml;
    const float* qm = qb + (size_t)m * 16;
    float corr = dot16(q0, q1, q2, q3, qm);
    float a1v = __expf(corr - rm1[b * NN + m]) * rcpf_(rs1[b * NN + m]) * ics1;
    const float4 pm = *(const float4*)(pb + (size_t)m * 4);
    float dd = pm.w + pn.w - 2.f * (pm.x * pn.x + pm.y * pn.y + pm.z * pn.z);
    dd = fmaxf(dd, 0.f);
    float l0 = (dd * icsd <= POS_COEF) ? a1v : 0.f;
    acc = fmaf(__expf(l0 - rm2[b * NN + m]), rcpf_(rs2[b * NN + m]), acc);
  }
  atomicAdd(&cs2[b * NN + n], acc);
}

// K7: recompute attn_final tile-by-tile, gma += xv @ attn (m-split x4, atomic finish)
__global__ __launch_bounds__(256) void k7_gma(
    const float* __restrict__ qt, const float* __restrict__ xyz4,
    const float* __restrict__ xvt,
    const float* __restrict__ rm1, const float* __restrict__ rs1,
    const float* __restrict__ rm2, const float* __restrict__ rs2,
    const float* __restrict__ cs1, const float* __restrict__ csd,
    const float* __restrict__ cs2, float* __restrict__ gma) {
  const int tid = threadIdx.x;
  const int bid = blockIdx.x;          // 512 = B * 64 * 4
  const int msl = bid & 3;
  const int nb = (bid >> 2) & 63;
  const int b = bid >> 8;
  const int n0 = nb << 6;
  const int mstart = msl << 10;
  __shared__ __align__(16) float attns[64 * 68];
  __shared__ __align__(16) float xvs[64 * 64];
  const float* qb = qt + (size_t)b * NN * 16;
  const float* pb = xyz4 + (size_t)b * NN * 4;
  // phase-A per-thread (fixed column na = n0 + ni)
  const int ni = tid & 63, aw = tid >> 6;
  const int na = n0 + ni;
  const float* qnp = qb + (size_t)na * 16;
  const float4 q0 = *(const float4*)(qnp + 0);
  const float4 q1 = *(const float4*)(qnp + 4);
  const float4 q2 = *(const float4*)(qnp + 8);
  const float4 q3 = *(const float4*)(qnp + 12);
  const float4 pn = *(const float4*)(pb + (size_t)na * 4);
  const float ics1 = rcpf_(1e-9f + cs1[b * NN + na]);
  const float icsd = rcpf_(1e-9f + csd[b * NN + na]);
  const float ics2 = rcpf_(1e-9f + cs2[b * NN + na]);
  // phase-B per-thread (4 channels x 4 columns)
  const int cq = tid & 15, nq = tid >> 4;
  float acc[4][4];
#pragma unroll
  for (int j = 0; j < 4; ++j)
#pragma unroll
    for (int i = 0; i < 4; ++i) acc[j][i] = 0.f;

  for (int mb2 = 0; mb2 < 16; ++mb2) {
    const int m0 = mstart + (mb2 << 6);
    __syncthreads();
    // stage xv block [64 m][64 c]
#pragma unroll
    for (int k2 = 0; k2 < 4; ++k2) {
      const int flat = (k2 << 10) + (tid << 2);
      *(float4*)(xvs + flat) = *(const float4*)(xvt + ((size_t)b * NN + m0) * 64 + flat);
    }
    // phase A: attn tile [64 m][64 n]
#pragma unroll
    for (int t = 0; t < 16; ++t) {
      const int m = __builtin_amdgcn_readfirstlane(m0 + aw + (t << 2));
      const float* qm = qb + (size_t)m * 16;
      float corr = dot16(q0, q1, q2, q3, qm);
      const float4 pm = *(const float4*)(pb + (size_t)m * 4);
      float a1v = __expf(corr - rm1[b * NN + m]) * rcpf_(rs1[b * NN + m]) * ics1;
      float dd = pm.w + pn.w - 2.f * (pm.x * pn.x + pm.y * pn.y + pm.z * pn.z);
      dd = fmaxf(dd, 0.f);
      float l0 = (dd * icsd <= POS_COEF) ? a1v : 0.f;
      float l2 = __expf(l0 - rm2[b * NN + m]) * rcpf_(rs2[b * NN + m]) * ics2;
      attns[(m - m0) * 68 + ni] = a1v + l2;
    }
    __syncthreads();
    // phase B: acc[j][i] += attn[m][nq*4+j] * xv[m][cq*4+i]
#pragma unroll 4
    for (int mm = 0; mm < 64; ++mm) {
      const float4 xv = *(const float4*)(xvs + (mm << 6) + (cq << 2));
      const float4 at = *(const float4*)(attns + mm * 68 + (nq << 2));
      acc[0][0] = fmaf(at.x, xv.x, acc[0][0]); acc[0][1] = fmaf(at.x, xv.y, acc[0][1]);
      acc[0][2] = fmaf(at.x, xv.z, acc[0][2]); acc[0][3] = fmaf(at.x, xv.w, acc[0][3]);
      acc[1][0] = fmaf(at.y, xv.x, acc[1][0]); acc[1][1] = fmaf(at.y, xv.y, acc[1][1]);
      acc[1][2] = fmaf(at.y, xv.z, acc[1][2]); acc[1][3] = fmaf(at.y, xv.w, acc[1][3]);
      acc[2][0] = fmaf(at.z, xv.x, acc[2][0]); acc[2][1] = fmaf(at.z, xv.y, acc[2][1]);
      acc[2][2] = fmaf(at.z, xv.z, acc[2][2]); acc[2][3] = fmaf(at.z, xv.w, acc[2][3]);
      acc[3][0] = fmaf(at.w, xv.x, acc[3][0]); acc[3][1] = fmaf(at.w, xv.y, acc[3][1]);
      acc[3][2] = fmaf(at.w, xv.z, acc[3][2]); acc[3][3] = fmaf(at.w, xv.w, acc[3][3]);
    }
  }
#pragma unroll
  for (int j = 0; j < 4; ++j) {
    float* g = gma + ((size_t)b * NN + n0 + (nq << 2) + j) * 64 + (cq << 2);
    atomicAdd(g + 0, acc[j][0]);
    atomicAdd(g + 1, acc[j][1]);
    atomicAdd(g + 2, acc[j][2]);
    atomicAdd(g + 3, acc[j][3]);
  }
}

// K8: res = Wt @ (motion - gma) + bt, IN PLACE over gma, plus GroupNorm partials
__global__ __launch_bounds__(256) void k8_res(
    const void* __restrict__ mot, const void* __restrict__ wt,
    const void* __restrict__ bt, const float* __restrict__ flag,
    float* __restrict__ gma_res, float* __restrict__ gn) {
  const bool f32 = flag[0] > 0.5f;
  const int tid = threadIdx.x;
  const int bid = blockIdx.x;           // 2048 = B * 1024
  const int b = bid >> 10;
  const int n0 = (bid & 1023) << 2;
  __shared__ float wtT[64 * 65];
  __shared__ float bts[64];
  __shared__ float md[4 * 64];
  __shared__ float gs[8], gss[8];
  for (int i = tid; i < 4096; i += 256) {
    int o = i & 63, c = i >> 6;
    wtT[c * 65 + o] = ldin(wt, o * 64 + c, f32);
  }
  if (tid < 64) bts[tid] = ldin(bt, tid, f32);
  if (tid < 8) { gs[tid] = 0.f; gss[tid] = 0.f; }
  {
    const int c = tid & 63, nl = tid >> 6;
    const int n = n0 + nl;
    float mv = ldin(mot, ((size_t)b * 64 + c) * NN + n, f32);
    md[nl * 64 + c] = mv - gma_res[((size_t)b * NN + n) * 64 + c];
  }
  __syncthreads();
  const int o = tid & 63, nl = tid >> 6;
  float acc = bts[o];
#pragma unroll 8
  for (int c = 0; c < 64; ++c)
    acc = fmaf(wtT[c * 65 + o], md[nl * 64 + c], acc);
  gma_res[((size_t)b * NN + n0 + nl) * 64 + o] = acc;  // in-place: same 256 elems read above
  atomicAdd(&gs[o >> 3], acc);
  atomicAdd(&gss[o >> 3], acc * acc);
  __syncthreads();
  if (tid < 8) atomicAdd(&gn[b * 8 + tid], gs[tid]);
  else if (tid < 16) atomicAdd(&gn[16 + b * 8 + (tid - 8)], gss[tid - 8]);
}

// K9: GroupNorm + PReLU + alpha * gr + motion -> out (dtype per flag)
__global__ __launch_bounds__(256) void k9_out(
    const float* __restrict__ res, const float* __restrict__ gn,
    const void* __restrict__ mot,
    const void* __restrict__ gnw, const void* __restrict__ gnb,
    const void* __restrict__ pa, const void* __restrict__ al,
    const float* __restrict__ flag, void* __restrict__ out) {
  const bool f32 = flag[0] > 0.5f;
  const int idx = blockIdx.x * 256 + threadIdx.x;   // (b,c,n), n fastest
  const int n = idx & 4095;
  const int c = (idx >> 12) & 63;
  const int b = idx >> 18;
  const int g = c >> 3;
  const float inv_cnt = 1.f / 32768.f;
  float mean = gn[b * 8 + g] * inv_cnt;
  float var = gn[16 + b * 8 + g] * inv_cnt - mean * mean;
  var = fmaxf(var, 0.f);
  float rstd = rsqrtf(var + 1e-5f);
  float r = res[((size_t)b * NN + n) * 64 + c];
  float y = (r - mean) * rstd * ldin(gnw, c, f32) + ldin(gnb, c, f32);
  float slope = ldin(pa, 0, f32);
  y = (y >= 0.f) ? y : slope * y;
  float o = ldin(al, 0, f32) * y + ldin(mot, idx, f32);
  if (f32) ((float*)out)[idx] = o;
  else     ((__hip_bfloat16*)out)[idx] = __float2bfloat16(o);
}

extern "C" void kernel_launch(void* const* d_in, const int* in_sizes, int n_in,
                              void* d_out, int out_size, void* d_ws, size_t ws_size,
                              hipStream_t stream) {
  const void* ctx = d_in[0];
  const void* mot = d_in[1];
  const void* xyz = d_in[2];
  const void* wqk = d_in[3];
  const void* wv  = d_in[4];
  const void* bv  = d_in[5];
  const void* wt  = d_in[6];
  const void* bt  = d_in[7];
  const void* gnw = d_in[8];
  const void* gnb = d_in[9];
  const void* pa  = d_in[10];
  const void* al  = d_in[11];
  float* ws = (float*)d_ws;

  if (ws_size < (size_t)WS_TOTAL * sizeof(float))
    fprintf(stderr, "[gma3d] WARNING ws_size=%zu < needed %zu\n",
            ws_size, (size_t)WS_TOTAL * sizeof(float));

  hipMemsetAsync(ws + OFF_CS1, 0, (size_t)ZERO_F * sizeof(float), stream);

  k0_detect<<<1, 256, 0, stream>>>((const unsigned short*)ctx, ws + OFF_FLAG);
  k1_q_xyz<<<32, 256, 0, stream>>>(ctx, xyz, wqk, ws + OFF_FLAG, ws + OFF_QT, ws + OFF_XYZ4);
  k2_xv<<<128, 256, 0, stream>>>(mot, wv, bv, ws + OFF_FLAG, ws + OFF_XVT);
  k3_rowstats1<<<512, 256, 0, stream>>>(ws + OFF_QT, ws + OFF_RM1, ws + OFF_RS1);
  k4_colsum1<<<512, 256, 0, stream>>>(ws + OFF_QT, ws + OFF_XYZ4,
                                      ws + OFF_RM1, ws + OFF_RS1,
                                      ws + OFF_CS1, ws + OFF_CSD);
  k5_rowstats2<<<512, 256, 0, stream>>>(ws + OFF_QT, ws + OFF_XYZ4,
                                        ws + OFF_RM1, ws + OFF_RS1,
                                        ws + OFF_CS1, ws + OFF_CSD,
                                        ws + OFF_RM2, ws + OFF_RS2);
  k6_colsum2<<<512, 256, 0, stream>>>(ws + OFF_QT, ws + OFF_XYZ4,
                                      ws + OFF_RM1, ws + OFF_RS1,
                                      ws + OFF_RM2, ws + OFF_RS2,
                                      ws + OFF_CS1, ws + OFF_CSD,
                                      ws + OFF_CS2);
  k7_gma<<<512, 256, 0, stream>>>(ws + OFF_QT, ws + OFF_XYZ4, ws + OFF_XVT,
                                  ws + OFF_RM1, ws + OFF_RS1,
                                  ws + OFF_RM2, ws + OFF_RS2,
                                  ws + OFF_CS1, ws + OFF_CSD, ws + OFF_CS2,
                                  ws + OFF_GMA);
  k8_res<<<2048, 256, 0, stream>>>(mot, wt, bt, ws + OFF_FLAG, ws + OFF_GMA, ws + OFF_GN);
  k9_out<<<2048, 256, 0, stream>>>(ws + OFF_GMA, ws + OFF_GN, mot, gnw, gnb, pa, al,
                                   ws + OFF_FLAG, d_out);
}

// Round 3
// 531.873 us; speedup vs baseline: 1.3202x; 1.3202x over previous
//
#include <hip/hip_runtime.h>
#include <hip/hip_bf16.h>
#include <cstdio>

#define NB 2
#define NN 4096
#define NC 64
#define NQ 16
#define POS_COEF 0.1f

// ---- workspace layout (float offsets) ----
#define OFF_QT   0u            // [B][N][16]  q (row-major per point)
#define OFF_XYZ4 131072u       // [B][N][4]   x,y,z,|p|^2
#define OFF_XVT  163840u       // [B][N][64]  xv
#define OFF_IRS1 688128u       // [B][N] 1/rowsum(exp corr)
#define OFF_IRS2 696320u       // [B][N] 1/rowsum(exp local0)
#define OFF_THR  704512u       // [B][N] 0.1*(1e-9+csd)
#define OFF_FLAG 712704u       // [16] dtype flag
// --- zeroed region below ---
#define OFF_SUMS 712720u       // [B][4] {Px,Py,Pz,S1}
#define OFF_CS1  712728u       // [B][N] colsum softmax1
#define OFF_CS2  720920u       // [B][N] colsum softmax2
#define OFF_GN   729112u       // [2][B][8]
#define OFF_GMA  729144u       // [B][N][64] gma acc -> res in k8
#define WS_TOTAL 1253432u
#define ZERO_F   (WS_TOTAL - OFF_SUMS)

__device__ __forceinline__ float b2f(__hip_bfloat16 x) { return __bfloat162float(x); }
__device__ __forceinline__ float rcpf_(float x) { return __builtin_amdgcn_rcpf(x); }

// dtype-agnostic input load (flag is wave-uniform)
__device__ __forceinline__ float ldin(const void* p, size_t i, bool f32) {
  return f32 ? ((const float*)p)[i]
             : __bfloat162float(((const __hip_bfloat16*)p)[i]);
}

__device__ __forceinline__ float dot16(const float4& a, const float4& b,
                                       const float4& c, const float4& d,
                                       const float* __restrict__ w) {
  float s = a.x * w[0];
  s = fmaf(a.y, w[1], s);  s = fmaf(a.z, w[2], s);  s = fmaf(a.w, w[3], s);
  s = fmaf(b.x, w[4], s);  s = fmaf(b.y, w[5], s);  s = fmaf(b.z, w[6], s);  s = fmaf(b.w, w[7], s);
  s = fmaf(c.x, w[8], s);  s = fmaf(c.y, w[9], s);  s = fmaf(c.z, w[10], s); s = fmaf(c.w, w[11], s);
  s = fmaf(d.x, w[12], s); s = fmaf(d.y, w[13], s); s = fmaf(d.z, w[14], s); s = fmaf(d.w, w[15], s);
  return s;
}

__device__ __forceinline__ float dot16v(const float4& a, const float4& b,
                                        const float4& c, const float4& d,
                                        const float4& e, const float4& f,
                                        const float4& g, const float4& h) {
  float s = a.x * e.x;
  s = fmaf(a.y, e.y, s);  s = fmaf(a.z, e.z, s);  s = fmaf(a.w, e.w, s);
  s = fmaf(b.x, f.x, s);  s = fmaf(b.y, f.y, s);  s = fmaf(b.z, f.z, s);  s = fmaf(b.w, f.w, s);
  s = fmaf(c.x, g.x, s);  s = fmaf(c.y, g.y, s);  s = fmaf(c.z, g.z, s);  s = fmaf(c.w, g.w, s);
  s = fmaf(d.x, h.x, s);  s = fmaf(d.y, h.y, s);  s = fmaf(d.z, h.z, s);  s = fmaf(d.w, h.w, s);
  return s;
}

// K0: detect input dtype (f32 misread as bf16 -> implausible exponents)
__global__ __launch_bounds__(256) void k0_detect(
    const unsigned short* __restrict__ ctx_u16, float* __restrict__ flag) {
  const int tid = threadIdx.x;
  int bad = 0;
  for (int i = tid; i < 8192; i += 256) {
    const unsigned short u = ctx_u16[i];
    const int e = (u >> 7) & 0xFF;
    if (e >= 134 || (e >= 1 && e <= 100)) bad++;
  }
  __shared__ int cnt;
  if (tid == 0) cnt = 0;
  __syncthreads();
  atomicAdd(&cnt, bad);
  __syncthreads();
  if (tid == 0) flag[0] = (cnt > 256) ? 1.0f : 0.0f;
}

// K1: q = Wqk @ ctx, xyz4 = {x,y,z,|p|^2}, batch sums {Px,Py,Pz,S1}
__global__ __launch_bounds__(256) void k1_q_xyz(
    const void* __restrict__ ctx, const void* __restrict__ xyz,
    const void* __restrict__ wqk, const float* __restrict__ flag,
    float* __restrict__ qt, float* __restrict__ xyz4, float* __restrict__ sums) {
  const bool f32 = flag[0] > 0.5f;
  const int tid = threadIdx.x;
  const int b = blockIdx.x >> 4;
  const int n = ((blockIdx.x & 15) << 8) + tid;
  __shared__ float wqT[NQ * NC];  // [c][o]
  for (int i = tid; i < NQ * NC; i += 256) {
    int o = i & 15, c = i >> 4;
    wqT[c * 16 + o] = ldin(wqk, o * 64 + c, f32);
  }
  __syncthreads();
  float4 a0 = {0,0,0,0}, a1 = {0,0,0,0}, a2 = {0,0,0,0}, a3 = {0,0,0,0};
  const size_t cbase = (size_t)b * 64 * NN + n;
#pragma unroll 4
  for (int c = 0; c < 64; ++c) {
    float x = ldin(ctx, cbase + (size_t)c * NN, f32);
    const float4 w0 = *(const float4*)(wqT + c * 16 + 0);
    const float4 w1 = *(const float4*)(wqT + c * 16 + 4);
    const float4 w2 = *(const float4*)(wqT + c * 16 + 8);
    const float4 w3 = *(const float4*)(wqT + c * 16 + 12);
    a0.x = fmaf(w0.x, x, a0.x); a0.y = fmaf(w0.y, x, a0.y); a0.z = fmaf(w0.z, x, a0.z); a0.w = fmaf(w0.w, x, a0.w);
    a1.x = fmaf(w1.x, x, a1.x); a1.y = fmaf(w1.y, x, a1.y); a1.z = fmaf(w1.z, x, a1.z); a1.w = fmaf(w1.w, x, a1.w);
    a2.x = fmaf(w2.x, x, a2.x); a2.y = fmaf(w2.y, x, a2.y); a2.z = fmaf(w2.z, x, a2.z); a2.w = fmaf(w2.w, x, a2.w);
    a3.x = fmaf(w3.x, x, a3.x); a3.y = fmaf(w3.y, x, a3.y); a3.z = fmaf(w3.z, x, a3.z); a3.w = fmaf(w3.w, x, a3.w);
  }
  float* qp = qt + (size_t)(b * NN + n) * 16;
  *(float4*)(qp + 0) = a0; *(float4*)(qp + 4) = a1;
  *(float4*)(qp + 8) = a2; *(float4*)(qp + 12) = a3;
  float xx = ldin(xyz, (size_t)(b * NN + n) * 3 + 0, f32);
  float yy = ldin(xyz, (size_t)(b * NN + n) * 3 + 1, f32);
  float zz = ldin(xyz, (size_t)(b * NN + n) * 3 + 2, f32);
  float4 p; p.x = xx; p.y = yy; p.z = zz; p.w = fmaf(xx, xx, fmaf(yy, yy, zz * zz));
  *(float4*)(xyz4 + (size_t)(b * NN + n) * 4) = p;
  // batch sums for analytic csd
  float sx = p.x, sy = p.y, sz = p.z, sw = p.w;
#pragma unroll
  for (int off = 32; off >= 1; off >>= 1) {
    sx += __shfl_xor(sx, off); sy += __shfl_xor(sy, off);
    sz += __shfl_xor(sz, off); sw += __shfl_xor(sw, off);
  }
  if ((tid & 63) == 0) {
    atomicAdd(&sums[b * 4 + 0], sx);
    atomicAdd(&sums[b * 4 + 1], sy);
    atomicAdd(&sums[b * 4 + 2], sz);
    atomicAdd(&sums[b * 4 + 3], sw);
  }
}

// K2: xv = Wv @ motion + bv  (stored [b][n][64])
__global__ __launch_bounds__(256) void k2_xv(
    const void* __restrict__ mot, const void* __restrict__ wv,
    const void* __restrict__ bv, const float* __restrict__ flag,
    float* __restrict__ xvt) {
  const bool f32 = flag[0] > 0.5f;
  const int tid = threadIdx.x;
  const int b = blockIdx.x >> 6;
  const int n = ((blockIdx.x & 63) << 6) + (tid >> 2);
  const int og = tid & 3;
  __shared__ float wvT[NC * NC];
  __shared__ float bvs[NC];
  for (int i = tid; i < NC * NC; i += 256) {
    int o = i & 63, c = i >> 6;
    wvT[c * 64 + o] = ldin(wv, o * 64 + c, f32);
  }
  if (tid < 64) bvs[tid] = ldin(bv, tid, f32);
  __syncthreads();
  float4 a0 = *(const float4*)(bvs + og * 16 + 0);
  float4 a1 = *(const float4*)(bvs + og * 16 + 4);
  float4 a2 = *(const float4*)(bvs + og * 16 + 8);
  float4 a3 = *(const float4*)(bvs + og * 16 + 12);
  const size_t mbase = (size_t)b * 64 * NN + n;
#pragma unroll 4
  for (int c = 0; c < 64; ++c) {
    float x = ldin(mot, mbase + (size_t)c * NN, f32);
    const float4 w0 = *(const float4*)(wvT + c * 64 + og * 16 + 0);
    const float4 w1 = *(const float4*)(wvT + c * 64 + og * 16 + 4);
    const float4 w2 = *(const float4*)(wvT + c * 64 + og * 16 + 8);
    const float4 w3 = *(const float4*)(wvT + c * 64 + og * 16 + 12);
    a0.x = fmaf(w0.x, x, a0.x); a0.y = fmaf(w0.y, x, a0.y); a0.z = fmaf(w0.z, x, a0.z); a0.w = fmaf(w0.w, x, a0.w);
    a1.x = fmaf(w1.x, x, a1.x); a1.y = fmaf(w1.y, x, a1.y); a1.z = fmaf(w1.z, x, a1.z); a1.w = fmaf(w1.w, x, a1.w);
    a2.x = fmaf(w2.x, x, a2.x); a2.y = fmaf(w2.y, x, a2.y); a2.z = fmaf(w2.z, x, a2.z); a2.w = fmaf(w2.w, x, a2.w);
    a3.x = fmaf(w3.x, x, a3.x); a3.y = fmaf(w3.y, x, a3.y); a3.z = fmaf(w3.z, x, a3.z); a3.w = fmaf(w3.w, x, a3.w);
  }
  float* dst = xvt + (size_t)(b * NN + n) * 64 + og * 16;
  *(float4*)(dst + 0) = a0; *(float4*)(dst + 4) = a1;
  *(float4*)(dst + 8) = a2; *(float4*)(dst + 12) = a3;
}

// K2b: thr[n] = 0.1*(1e-9 + csd[n]), csd analytic: S1 + N*sq_n - 2 p_n.P
__global__ __launch_bounds__(256) void k2b_thr(
    const float* __restrict__ xyz4, const float* __restrict__ sums,
    float* __restrict__ thr) {
  const int idx = blockIdx.x * 256 + threadIdx.x;   // 8192
  const int b = idx >> 12;
  const float4 pn = *(const float4*)(xyz4 + (size_t)idx * 4);
  const float Px = sums[b * 4 + 0], Py = sums[b * 4 + 1];
  const float Pz = sums[b * 4 + 2], S1 = sums[b * 4 + 3];
  float csd = fmaf((float)NN, pn.w, S1)
            - 2.f * (pn.x * Px + pn.y * Py + pn.z * Pz);
  thr[idx] = POS_COEF * (1e-9f + csd);
}

// P1: irs1[m] = 1/sum_n exp(corr_mn)   (unshifted; corr bounded ~25)
__global__ __launch_bounds__(256) void p1_rs1(
    const float* __restrict__ qt, float* __restrict__ irs1) {
  const int tid = threadIdx.x;
  const int b = blockIdx.x >> 9;            // 1024 blocks, 8 rows each
  const int m0 = (blockIdx.x & 511) << 3;
  const float* qb = qt + (size_t)b * NN * 16;
  float4 qm[8][4];
#pragma unroll
  for (int mi = 0; mi < 8; ++mi) {
    const float* qp = qb + (size_t)(m0 + mi) * 16;
#pragma unroll
    for (int k = 0; k < 4; ++k) qm[mi][k] = *(const float4*)(qp + 4 * k);
  }
  float acc[8];
#pragma unroll
  for (int i = 0; i < 8; ++i) acc[i] = 0.f;
  for (int chunk = 0; chunk < 16; ++chunk) {
    const int n = (chunk << 8) + tid;
    const float* qn = qb + (size_t)n * 16;
    const float4 q0 = *(const float4*)(qn + 0);
    const float4 q1 = *(const float4*)(qn + 4);
    const float4 q2 = *(const float4*)(qn + 8);
    const float4 q3 = *(const float4*)(qn + 12);
#pragma unroll
    for (int mi = 0; mi < 8; ++mi) {
      float corr = dot16v(q0, q1, q2, q3, qm[mi][0], qm[mi][1], qm[mi][2], qm[mi][3]);
      acc[mi] += __expf(fminf(corr, 80.f));
    }
  }
  __shared__ float red[8][4];
  const int lane = tid & 63, wid = tid >> 6;
#pragma unroll
  for (int mi = 0; mi < 8; ++mi) {
    float s = acc[mi];
#pragma unroll
    for (int off = 32; off >= 1; off >>= 1) s += __shfl_xor(s, off);
    if (lane == 0) red[mi][wid] = s;
  }
  __syncthreads();
  if (tid < 8) {
    float s = red[tid][0] + red[tid][1] + red[tid][2] + red[tid][3];
    irs1[b * NN + m0 + tid] = rcpf_(s);
  }
}

// P2: cs1[n] += sum_m exp(corr)*irs1[m]
__global__ __launch_bounds__(256) void p2_cs1(
    const float* __restrict__ qt, const float* __restrict__ irs1,
    float* __restrict__ cs1) {
  const int tid = threadIdx.x;
  const int b = blockIdx.x >> 9;            // 1024 = B*32*16
  const int ms = (blockIdx.x >> 4) & 31;
  const int cg = blockIdx.x & 15;
  const int n = (cg << 8) + tid;
  const int m0 = ms << 7;
  const float* qb = qt + (size_t)b * NN * 16;
  const float* qn = qb + (size_t)n * 16;
  const float4 q0 = *(const float4*)(qn + 0);
  const float4 q1 = *(const float4*)(qn + 4);
  const float4 q2 = *(const float4*)(qn + 8);
  const float4 q3 = *(const float4*)(qn + 12);
  float acc = 0.f;
#pragma unroll 4
  for (int ml = 0; ml < 128; ++ml) {
    const int m = m0 + ml;
    float corr = dot16(q0, q1, q2, q3, qb + (size_t)m * 16);
    acc = fmaf(__expf(fminf(corr, 80.f)), irs1[b * NN + m], acc);
  }
  atomicAdd(&cs1[b * NN + n], acc);
}

// P3: irs2[m] = 1/sum_n exp(local0_mn);  local0 = mask * attn1
__global__ __launch_bounds__(256) void p3_rs2(
    const float* __restrict__ qt, const float* __restrict__ xyz4,
    const float* __restrict__ irs1, const float* __restrict__ cs1,
    const float* __restrict__ thr, float* __restrict__ irs2) {
  const int tid = threadIdx.x;
  const int b = blockIdx.x >> 10;           // 2048 blocks, 4 rows each
  const int m0 = (blockIdx.x & 1023) << 2;
  const float* qb = qt + (size_t)b * NN * 16;
  const float* pb = xyz4 + (size_t)b * NN * 4;
  float4 qm[4][4], pm[4];
  float r1[4];
#pragma unroll
  for (int mi = 0; mi < 4; ++mi) {
    const float* qp = qb + (size_t)(m0 + mi) * 16;
#pragma unroll
    for (int k = 0; k < 4; ++k) qm[mi][k] = *(const float4*)(qp + 4 * k);
    pm[mi] = *(const float4*)(pb + (size_t)(m0 + mi) * 4);
    r1[mi] = irs1[b * NN + m0 + mi];
  }
  float acc[4] = {0.f, 0.f, 0.f, 0.f};
  for (int chunk = 0; chunk < 16; ++chunk) {
    const int n = (chunk << 8) + tid;
    const float* qn = qb + (size_t)n * 16;
    const float4 q0 = *(const float4*)(qn + 0);
    const float4 q1 = *(const float4*)(qn + 4);
    const float4 q2 = *(const float4*)(qn + 8);
    const float4 q3 = *(const float4*)(qn + 12);
    const float4 pn = *(const float4*)(pb + (size_t)n * 4);
    const float ics1 = rcpf_(1e-9f + cs1[b * NN + n]);
    const float thr_n = thr[b * NN + n];
#pragma unroll
    for (int mi = 0; mi < 4; ++mi) {
      float corr = dot16v(q0, q1, q2, q3, qm[mi][0], qm[mi][1], qm[mi][2], qm[mi][3]);
      float a1v = __expf(fminf(corr, 80.f)) * r1[mi] * ics1;
      float dd = pm[mi].w + pn.w
               - 2.f * (pm[mi].x * pn.x + pm[mi].y * pn.y + pm[mi].z * pn.z);
      dd = fmaxf(dd, 0.f);
      float l0 = (dd <= thr_n) ? a1v : 0.f;
      acc[mi] += __expf(l0);
    }
  }
  __shared__ float red[4][4];
  const int lane = tid & 63, wid = tid >> 6;
#pragma unroll
  for (int mi = 0; mi < 4; ++mi) {
    float s = acc[mi];
#pragma unroll
    for (int off = 32; off >= 1; off >>= 1) s += __shfl_xor(s, off);
    if (lane == 0) red[mi][wid] = s;
  }
  __syncthreads();
  if (tid < 4) {
    float s = red[tid][0] + red[tid][1] + red[tid][2] + red[tid][3];
    irs2[b * NN + m0 + tid] = rcpf_(s);
  }
}

// P4: cs2[n] += sum_m exp(local0)*irs2[m]
__global__ __launch_bounds__(256) void p4_cs2(
    const float* __restrict__ qt, const float* __restrict__ xyz4,
    const float* __restrict__ irs1, const float* __restrict__ irs2,
    const float* __restrict__ cs1, const float* __restrict__ thr,
    float* __restrict__ cs2) {
  const int tid = threadIdx.x;
  const int b = blockIdx.x >> 9;            // 1024 = B*32*16
  const int ms = (blockIdx.x >> 4) & 31;
  const int cg = blockIdx.x & 15;
  const int n = (cg << 8) + tid;
  const int m0 = ms << 7;
  const float* qb = qt + (size_t)b * NN * 16;
  const float* pb = xyz4 + (size_t)b * NN * 4;
  const float* qn = qb + (size_t)n * 16;
  const float4 q0 = *(const float4*)(qn + 0);
  const float4 q1 = *(const float4*)(qn + 4);
  const float4 q2 = *(const float4*)(qn + 8);
  const float4 q3 = *(const float4*)(qn + 12);
  const float4 pn = *(const float4*)(pb + (size_t)n * 4);
  const float ics1 = rcpf_(1e-9f + cs1[b * NN + n]);
  const float thr_n = thr[b * NN + n];
  float acc = 0.f;
#pragma unroll 2
  for (int ml = 0; ml < 128; ++ml) {
    const int m = m0 + ml;
    float corr = dot16(q0, q1, q2, q3, qb + (size_t)m * 16);
    float a1v = __expf(fminf(corr, 80.f)) * irs1[b * NN + m] * ics1;
    const float4 pm = *(const float4*)(pb + (size_t)m * 4);
    float dd = pm.w + pn.w - 2.f * (pm.x * pn.x + pm.y * pn.y + pm.z * pn.z);
    dd = fmaxf(dd, 0.f);
    float l0 = (dd <= thr_n) ? a1v : 0.f;
    acc = fmaf(__expf(l0), irs2[b * NN + m], acc);
  }
  atomicAdd(&cs2[b * NN + n], acc);
}

// K7: recompute attn_final tile-by-tile, gma += xv @ attn (m-split x4, atomic finish)
__global__ __launch_bounds__(256) void k7_gma(
    const float* __restrict__ qt, const float* __restrict__ xyz4,
    const float* __restrict__ xvt,
    const float* __restrict__ irs1, const float* __restrict__ irs2,
    const float* __restrict__ cs1, const float* __restrict__ cs2,
    const float* __restrict__ thr, float* __restrict__ gma) {
  const int tid = threadIdx.x;
  const int bid = blockIdx.x;          // 512 = B * 64 * 4
  const int msl = bid & 3;
  const int nb = (bid >> 2) & 63;
  const int b = bid >> 8;
  const int n0 = nb << 6;
  const int mstart = msl << 10;
  __shared__ __align__(16) float attns[64 * 68];
  __shared__ __align__(16) float xvs[64 * 64];
  const float* qb = qt + (size_t)b * NN * 16;
  const float* pb = xyz4 + (size_t)b * NN * 4;
  const int ni = tid & 63, aw = tid >> 6;
  const int na = n0 + ni;
  const float* qnp = qb + (size_t)na * 16;
  const float4 q0 = *(const float4*)(qnp + 0);
  const float4 q1 = *(const float4*)(qnp + 4);
  const float4 q2 = *(const float4*)(qnp + 8);
  const float4 q3 = *(const float4*)(qnp + 12);
  const float4 pn = *(const float4*)(pb + (size_t)na * 4);
  const float ics1 = rcpf_(1e-9f + cs1[b * NN + na]);
  const float ics2 = rcpf_(1e-9f + cs2[b * NN + na]);
  const float thr_n = thr[b * NN + na];
  const int cq = tid & 15, nq = tid >> 4;
  float acc[4][4];
#pragma unroll
  for (int j = 0; j < 4; ++j)
#pragma unroll
    for (int i = 0; i < 4; ++i) acc[j][i] = 0.f;

  for (int mb2 = 0; mb2 < 16; ++mb2) {
    const int m0 = mstart + (mb2 << 6);
    __syncthreads();
#pragma unroll
    for (int k2 = 0; k2 < 4; ++k2) {
      const int flat = (k2 << 10) + (tid << 2);
      *(float4*)(xvs + flat) = *(const float4*)(xvt + ((size_t)b * NN + m0) * 64 + flat);
    }
#pragma unroll
    for (int t = 0; t < 16; ++t) {
      const int m = __builtin_amdgcn_readfirstlane(m0 + aw + (t << 2));
      const float* qm = qb + (size_t)m * 16;
      float corr = dot16(q0, q1, q2, q3, qm);
      const float4 pm = *(const float4*)(pb + (size_t)m * 4);
      float a1v = __expf(fminf(corr, 80.f)) * irs1[b * NN + m] * ics1;
      float dd = pm.w + pn.w - 2.f * (pm.x * pn.x + pm.y * pn.y + pm.z * pn.z);
      dd = fmaxf(dd, 0.f);
      float l0 = (dd <= thr_n) ? a1v : 0.f;
      float l2 = __expf(l0) * irs2[b * NN + m] * ics2;
      attns[(m - m0) * 68 + ni] = a1v + l2;
    }
    __syncthreads();
#pragma unroll 4
    for (int mm = 0; mm < 64; ++mm) {
      const float4 xv = *(const float4*)(xvs + (mm << 6) + (cq << 2));
      const float4 at = *(const float4*)(attns + mm * 68 + (nq << 2));
      acc[0][0] = fmaf(at.x, xv.x, acc[0][0]); acc[0][1] = fmaf(at.x, xv.y, acc[0][1]);
      acc[0][2] = fmaf(at.x, xv.z, acc[0][2]); acc[0][3] = fmaf(at.x, xv.w, acc[0][3]);
      acc[1][0] = fmaf(at.y, xv.x, acc[1][0]); acc[1][1] = fmaf(at.y, xv.y, acc[1][1]);
      acc[1][2] = fmaf(at.y, xv.z, acc[1][2]); acc[1][3] = fmaf(at.y, xv.w, acc[1][3]);
      acc[2][0] = fmaf(at.z, xv.x, acc[2][0]); acc[2][1] = fmaf(at.z, xv.y, acc[2][1]);
      acc[2][2] = fmaf(at.z, xv.z, acc[2][2]); acc[2][3] = fmaf(at.z, xv.w, acc[2][3]);
      acc[3][0] = fmaf(at.w, xv.x, acc[3][0]); acc[3][1] = fmaf(at.w, xv.y, acc[3][1]);
      acc[3][2] = fmaf(at.w, xv.z, acc[3][2]); acc[3][3] = fmaf(at.w, xv.w, acc[3][3]);
    }
  }
#pragma unroll
  for (int j = 0; j < 4; ++j) {
    float* g = gma + ((size_t)b * NN + n0 + (nq << 2) + j) * 64 + (cq << 2);
    atomicAdd(g + 0, acc[j][0]);
    atomicAdd(g + 1, acc[j][1]);
    atomicAdd(g + 2, acc[j][2]);
    atomicAdd(g + 3, acc[j][3]);
  }
}

// K8: res = Wt @ (motion - gma) + bt, IN PLACE over gma, plus GroupNorm partials
__global__ __launch_bounds__(256) void k8_res(
    const void* __restrict__ mot, const void* __restrict__ wt,
    const void* __restrict__ bt, const float* __restrict__ flag,
    float* __restrict__ gma_res, float* __restrict__ gn) {
  const bool f32 = flag[0] > 0.5f;
  const int tid = threadIdx.x;
  const int bid = blockIdx.x;           // 2048 = B * 1024
  const int b = bid >> 10;
  const int n0 = (bid & 1023) << 2;
  __shared__ float wtT[64 * 65];
  __shared__ float bts[64];
  __shared__ float md[4 * 64];
  __shared__ float gs[8], gss[8];
  for (int i = tid; i < 4096; i += 256) {
    int o = i & 63, c = i >> 6;
    wtT[c * 65 + o] = ldin(wt, o * 64 + c, f32);
  }
  if (tid < 64) bts[tid] = ldin(bt, tid, f32);
  if (tid < 8) { gs[tid] = 0.f; gss[tid] = 0.f; }
  {
    const int c = tid & 63, nl = tid >> 6;
    const int n = n0 + nl;
    float mv = ldin(mot, ((size_t)b * 64 + c) * NN + n, f32);
    md[nl * 64 + c] = mv - gma_res[((size_t)b * NN + n) * 64 + c];
  }
  __syncthreads();
  const int o = tid & 63, nl = tid >> 6;
  float acc = bts[o];
#pragma unroll 8
  for (int c = 0; c < 64; ++c)
    acc = fmaf(wtT[c * 65 + o], md[nl * 64 + c], acc);
  gma_res[((size_t)b * NN + n0 + nl) * 64 + o] = acc;
  atomicAdd(&gs[o >> 3], acc);
  atomicAdd(&gss[o >> 3], acc * acc);
  __syncthreads();
  if (tid < 8) atomicAdd(&gn[b * 8 + tid], gs[tid]);
  else if (tid < 16) atomicAdd(&gn[16 + b * 8 + (tid - 8)], gss[tid - 8]);
}

// K9: GroupNorm + PReLU + alpha * gr + motion -> out
__global__ __launch_bounds__(256) void k9_out(
    const float* __restrict__ res, const float* __restrict__ gn,
    const void* __restrict__ mot,
    const void* __restrict__ gnw, const void* __restrict__ gnb,
    const void* __restrict__ pa, const void* __restrict__ al,
    const float* __restrict__ flag, void* __restrict__ out) {
  const bool f32 = flag[0] > 0.5f;
  const int idx = blockIdx.x * 256 + threadIdx.x;   // (b,c,n)
  const int n = idx & 4095;
  const int c = (idx >> 12) & 63;
  const int b = idx >> 18;
  const int g = c >> 3;
  const float inv_cnt = 1.f / 32768.f;
  float mean = gn[b * 8 + g] * inv_cnt;
  float var = gn[16 + b * 8 + g] * inv_cnt - mean * mean;
  var = fmaxf(var, 0.f);
  float rstd = rsqrtf(var + 1e-5f);
  float r = res[((size_t)b * NN + n) * 64 + c];
  float y = (r - mean) * rstd * ldin(gnw, c, f32) + ldin(gnb, c, f32);
  float slope = ldin(pa, 0, f32);
  y = (y >= 0.f) ? y : slope * y;
  float o = ldin(al, 0, f32) * y + ldin(mot, idx, f32);
  if (f32) ((float*)out)[idx] = o;
  else     ((__hip_bfloat16*)out)[idx] = __float2bfloat16(o);
}

extern "C" void kernel_launch(void* const* d_in, const int* in_sizes, int n_in,
                              void* d_out, int out_size, void* d_ws, size_t ws_size,
                              hipStream_t stream) {
  const void* ctx = d_in[0];
  const void* mot = d_in[1];
  const void* xyz = d_in[2];
  const void* wqk = d_in[3];
  const void* wv  = d_in[4];
  const void* bv  = d_in[5];
  const void* wt  = d_in[6];
  const void* bt  = d_in[7];
  const void* gnw = d_in[8];
  const void* gnb = d_in[9];
  const void* pa  = d_in[10];
  const void* al  = d_in[11];
  float* ws = (float*)d_ws;

  if (ws_size < (size_t)WS_TOTAL * sizeof(float))
    fprintf(stderr, "[gma3d] WARNING ws_size=%zu < needed %zu\n",
            ws_size, (size_t)WS_TOTAL * sizeof(float));

  hipMemsetAsync(ws + OFF_SUMS, 0, (size_t)ZERO_F * sizeof(float), stream);

  k0_detect<<<1, 256, 0, stream>>>((const unsigned short*)ctx, ws + OFF_FLAG);
  k1_q_xyz<<<32, 256, 0, stream>>>(ctx, xyz, wqk, ws + OFF_FLAG,
                                   ws + OFF_QT, ws + OFF_XYZ4, ws + OFF_SUMS);
  k2_xv<<<128, 256, 0, stream>>>(mot, wv, bv, ws + OFF_FLAG, ws + OFF_XVT);
  k2b_thr<<<32, 256, 0, stream>>>(ws + OFF_XYZ4, ws + OFF_SUMS, ws + OFF_THR);
  p1_rs1<<<1024, 256, 0, stream>>>(ws + OFF_QT, ws + OFF_IRS1);
  p2_cs1<<<1024, 256, 0, stream>>>(ws + OFF_QT, ws + OFF_IRS1, ws + OFF_CS1);
  p3_rs2<<<2048, 256, 0, stream>>>(ws + OFF_QT, ws + OFF_XYZ4,
                                   ws + OFF_IRS1, ws + OFF_CS1, ws + OFF_THR,
                                   ws + OFF_IRS2);
  p4_cs2<<<1024, 256, 0, stream>>>(ws + OFF_QT, ws + OFF_XYZ4,
                                   ws + OFF_IRS1, ws + OFF_IRS2,
                                   ws + OFF_CS1, ws + OFF_THR, ws + OFF_CS2);
  k7_gma<<<512, 256, 0, stream>>>(ws + OFF_QT, ws + OFF_XYZ4, ws + OFF_XVT,
                                  ws + OFF_IRS1, ws + OFF_IRS2,
                                  ws + OFF_CS1, ws + OFF_CS2, ws + OFF_THR,
                                  ws + OFF_GMA);
  k8_res<<<2048, 256, 0, stream>>>(mot, wt, bt, ws + OFF_FLAG, ws + OFF_GMA, ws + OFF_GN);
  k9_out<<<2048, 256, 0, stream>>>(ws + OFF_GMA, ws + OFF_GN, mot, gnw, gnb, pa, al,
                                   ws + OFF_FLAG, d_out);
}

// Round 4
// 530.970 us; speedup vs baseline: 1.3225x; 1.0017x over previous
//
#include <hip/hip_runtime.h>
#include <hip/hip_bf16.h>
#include <cstdio>

#define NB 2
#define NN 4096
#define NC 64
#define NQ 16
#define POS_COEF 0.1f

// ---- workspace layout (float offsets) ----
#define OFF_QT   0u            // [B][N][16]
#define OFF_XYZ4 131072u       // [B][N][4]
#define OFF_IRS1 163840u       // [B][N]
#define OFF_IRS2 172032u       // [B][N]
#define OFF_THR  180224u       // [B][N]
#define OFF_CS1  188416u       // [B][N] (written whole by p2, no zero)
#define OFF_CS2  196608u       // [B][N] (written whole by p4, no zero)
#define OFF_FLAG 204800u       // [16]
#define OFF_XVB  204816u       // [B][64][N] bf16 (262144 floats of space)
// --- zeroed region below ---
#define OFF_SUMS 466960u       // [B][4] {Px,Py,Pz,S1}
#define OFF_GN   466968u       // [2][B][8]
#define OFF_GMA  467000u       // [B][N][64] gma acc -> res in k8
#define WS_TOTAL 991288u
#define ZERO_F   (WS_TOTAL - OFF_SUMS)

using bf16x8 = __attribute__((ext_vector_type(8))) short;
using f32x4v = __attribute__((ext_vector_type(4))) float;

__device__ __forceinline__ float rcpf_(float x) { return __builtin_amdgcn_rcpf(x); }
__device__ __forceinline__ unsigned short f2bf(float x) {
  __hip_bfloat16 h = __float2bfloat16(x);
  return *(unsigned short*)&h;
}

// dtype-agnostic input load (flag is wave-uniform)
__device__ __forceinline__ float ldin(const void* p, size_t i, bool f32) {
  return f32 ? ((const float*)p)[i]
             : __bfloat162float(((const __hip_bfloat16*)p)[i]);
}

__device__ __forceinline__ float dot16(const float4& a, const float4& b,
                                       const float4& c, const float4& d,
                                       const float* __restrict__ w) {
  float s = a.x * w[0];
  s = fmaf(a.y, w[1], s);  s = fmaf(a.z, w[2], s);  s = fmaf(a.w, w[3], s);
  s = fmaf(b.x, w[4], s);  s = fmaf(b.y, w[5], s);  s = fmaf(b.z, w[6], s);  s = fmaf(b.w, w[7], s);
  s = fmaf(c.x, w[8], s);  s = fmaf(c.y, w[9], s);  s = fmaf(c.z, w[10], s); s = fmaf(c.w, w[11], s);
  s = fmaf(d.x, w[12], s); s = fmaf(d.y, w[13], s); s = fmaf(d.z, w[14], s); s = fmaf(d.w, w[15], s);
  return s;
}

__device__ __forceinline__ float dot16v(const float4& a, const float4& b,
                                        const float4& c, const float4& d,
                                        const float4& e, const float4& f,
                                        const float4& g, const float4& h) {
  float s = a.x * e.x;
  s = fmaf(a.y, e.y, s);  s = fmaf(a.z, e.z, s);  s = fmaf(a.w, e.w, s);
  s = fmaf(b.x, f.x, s);  s = fmaf(b.y, f.y, s);  s = fmaf(b.z, f.z, s);  s = fmaf(b.w, f.w, s);
  s = fmaf(c.x, g.x, s);  s = fmaf(c.y, g.y, s);  s = fmaf(c.z, g.z, s);  s = fmaf(c.w, g.w, s);
  s = fmaf(d.x, h.x, s);  s = fmaf(d.y, h.y, s);  s = fmaf(d.z, h.z, s);  s = fmaf(d.w, h.w, s);
  return s;
}

// K0: detect input dtype (f32 misread as bf16 -> implausible exponents)
__global__ __launch_bounds__(256) void k0_detect(
    const unsigned short* __restrict__ ctx_u16, float* __restrict__ flag) {
  const int tid = threadIdx.x;
  int bad = 0;
  for (int i = tid; i < 8192; i += 256) {
    const unsigned short u = ctx_u16[i];
    const int e = (u >> 7) & 0xFF;
    if (e >= 134 || (e >= 1 && e <= 100)) bad++;
  }
  __shared__ int cnt;
  if (tid == 0) cnt = 0;
  __syncthreads();
  atomicAdd(&cnt, bad);
  __syncthreads();
  if (tid == 0) flag[0] = (cnt > 256) ? 1.0f : 0.0f;
}

// K1: q = Wqk @ ctx, xyz4 = {x,y,z,|p|^2}, batch sums {Px,Py,Pz,S1}
__global__ __launch_bounds__(256) void k1_q_xyz(
    const void* __restrict__ ctx, const void* __restrict__ xyz,
    const void* __restrict__ wqk, const float* __restrict__ flag,
    float* __restrict__ qt, float* __restrict__ xyz4, float* __restrict__ sums) {
  const bool f32 = flag[0] > 0.5f;
  const int tid = threadIdx.x;
  const int b = blockIdx.x >> 4;
  const int n = ((blockIdx.x & 15) << 8) + tid;
  __shared__ float wqT[NQ * NC];  // [c][o]
  for (int i = tid; i < NQ * NC; i += 256) {
    int o = i & 15, c = i >> 4;
    wqT[c * 16 + o] = ldin(wqk, o * 64 + c, f32);
  }
  __syncthreads();
  float4 a0 = {0,0,0,0}, a1 = {0,0,0,0}, a2 = {0,0,0,0}, a3 = {0,0,0,0};
  const size_t cbase = (size_t)b * 64 * NN + n;
#pragma unroll 4
  for (int c = 0; c < 64; ++c) {
    float x = ldin(ctx, cbase + (size_t)c * NN, f32);
    const float4 w0 = *(const float4*)(wqT + c * 16 + 0);
    const float4 w1 = *(const float4*)(wqT + c * 16 + 4);
    const float4 w2 = *(const float4*)(wqT + c * 16 + 8);
    const float4 w3 = *(const float4*)(wqT + c * 16 + 12);
    a0.x = fmaf(w0.x, x, a0.x); a0.y = fmaf(w0.y, x, a0.y); a0.z = fmaf(w0.z, x, a0.z); a0.w = fmaf(w0.w, x, a0.w);
    a1.x = fmaf(w1.x, x, a1.x); a1.y = fmaf(w1.y, x, a1.y); a1.z = fmaf(w1.z, x, a1.z); a1.w = fmaf(w1.w, x, a1.w);
    a2.x = fmaf(w2.x, x, a2.x); a2.y = fmaf(w2.y, x, a2.y); a2.z = fmaf(w2.z, x, a2.z); a2.w = fmaf(w2.w, x, a2.w);
    a3.x = fmaf(w3.x, x, a3.x); a3.y = fmaf(w3.y, x, a3.y); a3.z = fmaf(w3.z, x, a3.z); a3.w = fmaf(w3.w, x, a3.w);
  }
  float* qp = qt + (size_t)(b * NN + n) * 16;
  *(float4*)(qp + 0) = a0; *(float4*)(qp + 4) = a1;
  *(float4*)(qp + 8) = a2; *(float4*)(qp + 12) = a3;
  float xx = ldin(xyz, (size_t)(b * NN + n) * 3 + 0, f32);
  float yy = ldin(xyz, (size_t)(b * NN + n) * 3 + 1, f32);
  float zz = ldin(xyz, (size_t)(b * NN + n) * 3 + 2, f32);
  float4 p; p.x = xx; p.y = yy; p.z = zz; p.w = fmaf(xx, xx, fmaf(yy, yy, zz * zz));
  *(float4*)(xyz4 + (size_t)(b * NN + n) * 4) = p;
  float sx = p.x, sy = p.y, sz = p.z, sw = p.w;
#pragma unroll
  for (int off = 32; off >= 1; off >>= 1) {
    sx += __shfl_xor(sx, off); sy += __shfl_xor(sy, off);
    sz += __shfl_xor(sz, off); sw += __shfl_xor(sw, off);
  }
  if ((tid & 63) == 0) {
    atomicAdd(&sums[b * 4 + 0], sx);
    atomicAdd(&sums[b * 4 + 1], sy);
    atomicAdd(&sums[b * 4 + 2], sz);
    atomicAdd(&sums[b * 4 + 3], sw);
  }
}

// K2: xv = Wv @ motion + bv, stored bf16 CHANNEL-MAJOR [b][c][n] for k7 B-operand
__global__ __launch_bounds__(256) void k2_xv(
    const void* __restrict__ mot, const void* __restrict__ wv,
    const void* __restrict__ bv, const float* __restrict__ flag,
    unsigned short* __restrict__ xvb) {
  const bool f32 = flag[0] > 0.5f;
  const int tid = threadIdx.x;
  const int b = blockIdx.x >> 6;
  const int n = ((blockIdx.x & 63) << 6) + (tid >> 2);
  const int og = tid & 3;
  __shared__ float wvT[NC * NC];
  __shared__ float bvs[NC];
  for (int i = tid; i < NC * NC; i += 256) {
    int o = i & 63, c = i >> 6;
    wvT[c * 64 + o] = ldin(wv, o * 64 + c, f32);
  }
  if (tid < 64) bvs[tid] = ldin(bv, tid, f32);
  __syncthreads();
  float4 a0 = *(const float4*)(bvs + og * 16 + 0);
  float4 a1 = *(const float4*)(bvs + og * 16 + 4);
  float4 a2 = *(const float4*)(bvs + og * 16 + 8);
  float4 a3 = *(const float4*)(bvs + og * 16 + 12);
  const size_t mbase = (size_t)b * 64 * NN + n;
#pragma unroll 4
  for (int c = 0; c < 64; ++c) {
    float x = ldin(mot, mbase + (size_t)c * NN, f32);
    const float4 w0 = *(const float4*)(wvT + c * 64 + og * 16 + 0);
    const float4 w1 = *(const float4*)(wvT + c * 64 + og * 16 + 4);
    const float4 w2 = *(const float4*)(wvT + c * 64 + og * 16 + 8);
    const float4 w3 = *(const float4*)(wvT + c * 64 + og * 16 + 12);
    a0.x = fmaf(w0.x, x, a0.x); a0.y = fmaf(w0.y, x, a0.y); a0.z = fmaf(w0.z, x, a0.z); a0.w = fmaf(w0.w, x, a0.w);
    a1.x = fmaf(w1.x, x, a1.x); a1.y = fmaf(w1.y, x, a1.y); a1.z = fmaf(w1.z, x, a1.z); a1.w = fmaf(w1.w, x, a1.w);
    a2.x = fmaf(w2.x, x, a2.x); a2.y = fmaf(w2.y, x, a2.y); a2.z = fmaf(w2.z, x, a2.z); a2.w = fmaf(w2.w, x, a2.w);
    a3.x = fmaf(w3.x, x, a3.x); a3.y = fmaf(w3.y, x, a3.y); a3.z = fmaf(w3.z, x, a3.z); a3.w = fmaf(w3.w, x, a3.w);
  }
  unsigned short* xb = xvb + (size_t)b * 64 * NN + n;
  const int o0 = og * 16;
  xb[(size_t)(o0 + 0) * NN] = f2bf(a0.x);  xb[(size_t)(o0 + 1) * NN] = f2bf(a0.y);
  xb[(size_t)(o0 + 2) * NN] = f2bf(a0.z);  xb[(size_t)(o0 + 3) * NN] = f2bf(a0.w);
  xb[(size_t)(o0 + 4) * NN] = f2bf(a1.x);  xb[(size_t)(o0 + 5) * NN] = f2bf(a1.y);
  xb[(size_t)(o0 + 6) * NN] = f2bf(a1.z);  xb[(size_t)(o0 + 7) * NN] = f2bf(a1.w);
  xb[(size_t)(o0 + 8) * NN] = f2bf(a2.x);  xb[(size_t)(o0 + 9) * NN] = f2bf(a2.y);
  xb[(size_t)(o0 +10) * NN] = f2bf(a2.z);  xb[(size_t)(o0 +11) * NN] = f2bf(a2.w);
  xb[(size_t)(o0 +12) * NN] = f2bf(a3.x);  xb[(size_t)(o0 +13) * NN] = f2bf(a3.y);
  xb[(size_t)(o0 +14) * NN] = f2bf(a3.z);  xb[(size_t)(o0 +15) * NN] = f2bf(a3.w);
}

// K2b: thr[n] = 0.1*(1e-9 + csd[n]), csd analytic
__global__ __launch_bounds__(256) void k2b_thr(
    const float* __restrict__ xyz4, const float* __restrict__ sums,
    float* __restrict__ thr) {
  const int idx = blockIdx.x * 256 + threadIdx.x;   // 8192
  const int b = idx >> 12;
  const float4 pn = *(const float4*)(xyz4 + (size_t)idx * 4);
  const float Px = sums[b * 4 + 0], Py = sums[b * 4 + 1];
  const float Pz = sums[b * 4 + 2], S1 = sums[b * 4 + 3];
  float csd = fmaf((float)NN, pn.w, S1)
            - 2.f * (pn.x * Px + pn.y * Py + pn.z * Pz);
  thr[idx] = POS_COEF * (1e-9f + csd);
}

// P1: irs1[m] = 1/sum_n exp(corr_mn)
__global__ __launch_bounds__(256) void p1_rs1(
    const float* __restrict__ qt, float* __restrict__ irs1) {
  const int tid = threadIdx.x;
  const int b = blockIdx.x >> 9;
  const int m0 = (blockIdx.x & 511) << 3;
  const float* qb = qt + (size_t)b * NN * 16;
  float4 qm[8][4];
#pragma unroll
  for (int mi = 0; mi < 8; ++mi) {
    const float* qp = qb + (size_t)(m0 + mi) * 16;
#pragma unroll
    for (int k = 0; k < 4; ++k) qm[mi][k] = *(const float4*)(qp + 4 * k);
  }
  float acc[8];
#pragma unroll
  for (int i = 0; i < 8; ++i) acc[i] = 0.f;
  for (int chunk = 0; chunk < 16; ++chunk) {
    const int n = (chunk << 8) + tid;
    const float* qn = qb + (size_t)n * 16;
    const float4 q0 = *(const float4*)(qn + 0);
    const float4 q1 = *(const float4*)(qn + 4);
    const float4 q2 = *(const float4*)(qn + 8);
    const float4 q3 = *(const float4*)(qn + 12);
#pragma unroll
    for (int mi = 0; mi < 8; ++mi) {
      float corr = dot16v(q0, q1, q2, q3, qm[mi][0], qm[mi][1], qm[mi][2], qm[mi][3]);
      acc[mi] += __expf(fminf(corr, 80.f));
    }
  }
  __shared__ float red[8][4];
  const int lane = tid & 63, wid = tid >> 6;
#pragma unroll
  for (int mi = 0; mi < 8; ++mi) {
    float s = acc[mi];
#pragma unroll
    for (int off = 32; off >= 1; off >>= 1) s += __shfl_xor(s, off);
    if (lane == 0) red[mi][wid] = s;
  }
  __syncthreads();
  if (tid < 8) {
    float s = red[tid][0] + red[tid][1] + red[tid][2] + red[tid][3];
    irs1[b * NN + m0 + tid] = rcpf_(s);
  }
}

// P2: cs1[n] = sum_m exp(corr)*irs1[m]  (block owns 8 n, no atomics)
__global__ __launch_bounds__(256) void p2_cs1(
    const float* __restrict__ qt, const float* __restrict__ irs1,
    float* __restrict__ cs1) {
  const int tid = threadIdx.x;
  const int b = blockIdx.x >> 9;
  const int n0 = (blockIdx.x & 511) << 3;
  const float* qb = qt + (size_t)b * NN * 16;
  float4 qn[8][4];
#pragma unroll
  for (int i = 0; i < 8; ++i) {
    const float* qp = qb + (size_t)(n0 + i) * 16;
#pragma unroll
    for (int k = 0; k < 4; ++k) qn[i][k] = *(const float4*)(qp + 4 * k);
  }
  float acc[8];
#pragma unroll
  for (int i = 0; i < 8; ++i) acc[i] = 0.f;
  for (int chunk = 0; chunk < 16; ++chunk) {
    const int m = (chunk << 8) + tid;
    const float* qmp = qb + (size_t)m * 16;
    const float4 m0_ = *(const float4*)(qmp + 0);
    const float4 m1_ = *(const float4*)(qmp + 4);
    const float4 m2_ = *(const float4*)(qmp + 8);
    const float4 m3_ = *(const float4*)(qmp + 12);
    const float r1 = irs1[b * NN + m];
#pragma unroll
    for (int i = 0; i < 8; ++i) {
      float corr = dot16v(m0_, m1_, m2_, m3_, qn[i][0], qn[i][1], qn[i][2], qn[i][3]);
      acc[i] = fmaf(__expf(fminf(corr, 80.f)), r1, acc[i]);
    }
  }
  __shared__ float red[8][4];
  const int lane = tid & 63, wid = tid >> 6;
#pragma unroll
  for (int i = 0; i < 8; ++i) {
    float s = acc[i];
#pragma unroll
    for (int off = 32; off >= 1; off >>= 1) s += __shfl_xor(s, off);
    if (lane == 0) red[i][wid] = s;
  }
  __syncthreads();
  if (tid < 8) {
    cs1[b * NN + n0 + tid] = red[tid][0] + red[tid][1] + red[tid][2] + red[tid][3];
  }
}

// P3: irs2[m] = 1/sum_n exp(local0_mn)
__global__ __launch_bounds__(256) void p3_rs2(
    const float* __restrict__ qt, const float* __restrict__ xyz4,
    const float* __restrict__ irs1, const float* __restrict__ cs1,
    const float* __restrict__ thr, float* __restrict__ irs2) {
  const int tid = threadIdx.x;
  const int b = blockIdx.x >> 10;
  const int m0 = (blockIdx.x & 1023) << 2;
  const float* qb = qt + (size_t)b * NN * 16;
  const float* pb = xyz4 + (size_t)b * NN * 4;
  float4 qm[4][4], pm[4];
  float r1[4];
#pragma unroll
  for (int mi = 0; mi < 4; ++mi) {
    const float* qp = qb + (size_t)(m0 + mi) * 16;
#pragma unroll
    for (int k = 0; k < 4; ++k) qm[mi][k] = *(const float4*)(qp + 4 * k);
    pm[mi] = *(const float4*)(pb + (size_t)(m0 + mi) * 4);
    r1[mi] = irs1[b * NN + m0 + mi];
  }
  float acc[4] = {0.f, 0.f, 0.f, 0.f};
  for (int chunk = 0; chunk < 16; ++chunk) {
    const int n = (chunk << 8) + tid;
    const float* qn = qb + (size_t)n * 16;
    const float4 q0 = *(const float4*)(qn + 0);
    const float4 q1 = *(const float4*)(qn + 4);
    const float4 q2 = *(const float4*)(qn + 8);
    const float4 q3 = *(const float4*)(qn + 12);
    const float4 pn = *(const float4*)(pb + (size_t)n * 4);
    const float ics1 = rcpf_(1e-9f + cs1[b * NN + n]);
    const float thr_n = thr[b * NN + n];
#pragma unroll
    for (int mi = 0; mi < 4; ++mi) {
      float corr = dot16v(q0, q1, q2, q3, qm[mi][0], qm[mi][1], qm[mi][2], qm[mi][3]);
      float a1v = __expf(fminf(corr, 80.f)) * r1[mi] * ics1;
      float dd = pm[mi].w + pn.w
               - 2.f * (pm[mi].x * pn.x + pm[mi].y * pn.y + pm[mi].z * pn.z);
      dd = fmaxf(dd, 0.f);
      float l0 = (dd <= thr_n) ? a1v : 0.f;
      acc[mi] += __expf(l0);
    }
  }
  __shared__ float red[4][4];
  const int lane = tid & 63, wid = tid >> 6;
#pragma unroll
  for (int mi = 0; mi < 4; ++mi) {
    float s = acc[mi];
#pragma unroll
    for (int off = 32; off >= 1; off >>= 1) s += __shfl_xor(s, off);
    if (lane == 0) red[mi][wid] = s;
  }
  __syncthreads();
  if (tid < 4) {
    float s = red[tid][0] + red[tid][1] + red[tid][2] + red[tid][3];
    irs2[b * NN + m0 + tid] = rcpf_(s);
  }
}

// P4: cs2[n] = sum_m exp(local0)*irs2[m]  (block owns 4 n, no atomics)
__global__ __launch_bounds__(256) void p4_cs2(
    const float* __restrict__ qt, const float* __restrict__ xyz4,
    const float* __restrict__ irs1, const float* __restrict__ irs2,
    const float* __restrict__ cs1, const float* __restrict__ thr,
    float* __restrict__ cs2) {
  const int tid = threadIdx.x;
  const int b = blockIdx.x >> 10;
  const int n0 = (blockIdx.x & 1023) << 2;
  const float* qb = qt + (size_t)b * NN * 16;
  const float* pb = xyz4 + (size_t)b * NN * 4;
  float4 qn[4][4], pn4[4];
  float ics1n[4], thrn[4];
#pragma unroll
  for (int i = 0; i < 4; ++i) {
    const float* qp = qb + (size_t)(n0 + i) * 16;
#pragma unroll
    for (int k = 0; k < 4; ++k) qn[i][k] = *(const float4*)(qp + 4 * k);
    pn4[i] = *(const float4*)(pb + (size_t)(n0 + i) * 4);
    ics1n[i] = rcpf_(1e-9f + cs1[b * NN + n0 + i]);
    thrn[i] = thr[b * NN + n0 + i];
  }
  float acc[4] = {0.f, 0.f, 0.f, 0.f};
  for (int chunk = 0; chunk < 16; ++chunk) {
    const int m = (chunk << 8) + tid;
    const float* qmp = qb + (size_t)m * 16;
    const float4 m0_ = *(const float4*)(qmp + 0);
    const float4 m1_ = *(const float4*)(qmp + 4);
    const float4 m2_ = *(const float4*)(qmp + 8);
    const float4 m3_ = *(const float4*)(qmp + 12);
    const float4 pm = *(const float4*)(pb + (size_t)m * 4);
    const float r1 = irs1[b * NN + m];
    const float r2 = irs2[b * NN + m];
    const float E = __expf(fminf(dot16v(m0_, m1_, m2_, m3_,
                                        qn[0][0], qn[0][1], qn[0][2], qn[0][3]), 80.f));
    // note: corr must be computed per (m,n): do each i separately
#pragma unroll
    for (int i = 0; i < 4; ++i) {
      float corr = dot16v(m0_, m1_, m2_, m3_, qn[i][0], qn[i][1], qn[i][2], qn[i][3]);
      float Ei = (i == 0) ? E : __expf(fminf(corr, 80.f));
      float a1v = Ei * r1 * ics1n[i];
      float dd = pm.w + pn4[i].w
               - 2.f * (pm.x * pn4[i].x + pm.y * pn4[i].y + pm.z * pn4[i].z);
      dd = fmaxf(dd, 0.f);
      float l0 = (dd <= thrn[i]) ? a1v : 0.f;
      acc[i] = fmaf(__expf(l0), r2, acc[i]);
    }
  }
  __shared__ float red[4][4];
  const int lane = tid & 63, wid = tid >> 6;
#pragma unroll
  for (int i = 0; i < 4; ++i) {
    float s = acc[i];
#pragma unroll
    for (int off = 32; off >= 1; off >>= 1) s += __shfl_xor(s, off);
    if (lane == 0) red[i][wid] = s;
  }
  __syncthreads();
  if (tid < 4) {
    cs2[b * NN + n0 + tid] = red[tid][0] + red[tid][1] + red[tid][2] + red[tid][3];
  }
}

// K7: attn tile (phase A, f32 scalar) -> bf16 LDS -> MFMA with xv (phase B)
// grid 1024 = B * 64 n-tiles * 8 m-split; LDS 18.4 KB
__global__ __launch_bounds__(256) void k7_gma(
    const float* __restrict__ qt, const float* __restrict__ xyz4,
    const unsigned short* __restrict__ xvb,
    const float* __restrict__ irs1, const float* __restrict__ irs2,
    const float* __restrict__ cs1, const float* __restrict__ cs2,
    const float* __restrict__ thr, float* __restrict__ gma) {
  const int tid = threadIdx.x;
  const int bid = blockIdx.x;
  const int msl = bid & 7;
  const int nb = (bid >> 3) & 63;
  const int b = bid >> 9;
  const int n0 = nb << 6;
  const int mstart = msl << 9;
  // stride 72 bf16 = 144 B: 16B-aligned rows, ~2-way max bank aliasing
  __shared__ __align__(16) unsigned short attns[64 * 72];  // [n][m] A-layout
  __shared__ __align__(16) unsigned short xvs[64 * 72];    // [c][m] B-layout
  const float* qb = qt + (size_t)b * NN * 16;
  const float* pb = xyz4 + (size_t)b * NN * 4;
  // phase-A constants (thread owns column na = n0 + ni)
  const int ni = tid & 63, aw = tid >> 6;
  const int na = n0 + ni;
  const float* qnp = qb + (size_t)na * 16;
  const float4 q0 = *(const float4*)(qnp + 0);
  const float4 q1 = *(const float4*)(qnp + 4);
  const float4 q2 = *(const float4*)(qnp + 8);
  const float4 q3 = *(const float4*)(qnp + 12);
  const float4 pn = *(const float4*)(pb + (size_t)na * 4);
  const float ics1 = rcpf_(1e-9f + cs1[b * NN + na]);
  const float ics2 = rcpf_(1e-9f + cs2[b * NN + na]);
  const float thr_n = thr[b * NN + na];
  // phase-B ids
  const int lane = tid & 63, wv = tid >> 6;
  const int lr = lane & 15, quad = lane >> 4;
  const int nw = wv << 4;
  f32x4v acc[4] = {{0,0,0,0},{0,0,0,0},{0,0,0,0},{0,0,0,0}};

  for (int mt = 0; mt < 8; ++mt) {
    const int m0 = mstart + (mt << 6);
    __syncthreads();
    // stage xv [c][m]: 64 rows x 128 B, 4 threads/row x 32 B
    {
      const int c = tid >> 2, part = tid & 3;
      const unsigned short* src = xvb + ((size_t)b * 64 + c) * NN + m0 + part * 16;
      unsigned short* dst = xvs + c * 72 + part * 16;
      *(uint4*)dst = *(const uint4*)src;
      *(uint4*)(dst + 8) = *(const uint4*)(src + 8);
    }
    // phase A: attn[n][m] bf16
#pragma unroll
    for (int t = 0; t < 16; ++t) {
      const int m = __builtin_amdgcn_readfirstlane(m0 + aw + (t << 2));
      const float* qm = qb + (size_t)m * 16;
      float corr = dot16(q0, q1, q2, q3, qm);
      const float4 pm = *(const float4*)(pb + (size_t)m * 4);
      float a1v = __expf(fminf(corr, 80.f)) * irs1[b * NN + m] * ics1;
      float dd = pm.w + pn.w - 2.f * (pm.x * pn.x + pm.y * pn.y + pm.z * pn.z);
      dd = fmaxf(dd, 0.f);
      float l0 = (dd <= thr_n) ? a1v : 0.f;
      float l2 = __expf(l0) * irs2[b * NN + m] * ics2;
      attns[ni * 72 + (m - m0)] = f2bf(a1v + l2);
    }
    __syncthreads();
    // phase B: D[n][c] += A[n][k=m] * B[k=m][c], K=64 via 2 halves
#pragma unroll
    for (int h = 0; h < 2; ++h) {
      const bf16x8 a = *(const bf16x8*)(attns + (nw + lr) * 72 + h * 32 + quad * 8);
#pragma unroll
      for (int ct = 0; ct < 4; ++ct) {
        const bf16x8 bb = *(const bf16x8*)(xvs + (ct * 16 + lr) * 72 + h * 32 + quad * 8);
        acc[ct] = __builtin_amdgcn_mfma_f32_16x16x32_bf16(a, bb, acc[ct], 0, 0, 0);
      }
    }
  }
  // epilogue: C-layout col=lane&15 (c), row=quad*4+reg (n)
#pragma unroll
  for (int ct = 0; ct < 4; ++ct) {
    const int c = ct * 16 + lr;
#pragma unroll
    for (int r = 0; r < 4; ++r) {
      const int n = n0 + nw + quad * 4 + r;
      atomicAdd(gma + ((size_t)b * NN + n) * 64 + c, acc[ct][r]);
    }
  }
}

// K8: res = Wt @ (motion - gma) + bt, in place over gma, + GroupNorm partials
__global__ __launch_bounds__(256) void k8_res(
    const void* __restrict__ mot, const void* __restrict__ wt,
    const void* __restrict__ bt, const float* __restrict__ flag,
    float* __restrict__ gma_res, float* __restrict__ gn) {
  const bool f32 = flag[0] > 0.5f;
  const int tid = threadIdx.x;
  const int bid = blockIdx.x;           // 1024 = B * 512
  const int b = bid >> 9;
  const int n0 = (bid & 511) << 3;
  __shared__ float wtT[64 * 65];
  __shared__ float bts[64];
  __shared__ float md[8 * 64];
  __shared__ float gs[8], gss[8];
  for (int i = tid; i < 4096; i += 256) {
    int o = i & 63, c = i >> 6;
    wtT[c * 65 + o] = ldin(wt, o * 64 + c, f32);
  }
  if (tid < 64) bts[tid] = ldin(bt, tid, f32);
  if (tid < 8) { gs[tid] = 0.f; gss[tid] = 0.f; }
#pragma unroll
  for (int r = 0; r < 2; ++r) {
    const int idx = tid * 2 + r;
    const int c = idx & 63, nl = idx >> 6;
    md[nl * 64 + c] = ldin(mot, ((size_t)b * 64 + c) * NN + n0 + nl, f32)
                    - gma_res[((size_t)b * NN + n0 + nl) * 64 + c];
  }
  __syncthreads();
  const int o = tid & 63, ng = tid >> 6;
  const int nl0 = ng * 2, nl1 = ng * 2 + 1;
  float a0 = bts[o], a1 = bts[o];
#pragma unroll 8
  for (int c = 0; c < 64; ++c) {
    float w = wtT[c * 65 + o];
    a0 = fmaf(w, md[nl0 * 64 + c], a0);
    a1 = fmaf(w, md[nl1 * 64 + c], a1);
  }
  gma_res[((size_t)b * NN + n0 + nl0) * 64 + o] = a0;
  gma_res[((size_t)b * NN + n0 + nl1) * 64 + o] = a1;
  atomicAdd(&gs[o >> 3], a0 + a1);
  atomicAdd(&gss[o >> 3], a0 * a0 + a1 * a1);
  __syncthreads();
  if (tid < 8) atomicAdd(&gn[b * 8 + tid], gs[tid]);
  else if (tid < 16) atomicAdd(&gn[16 + b * 8 + (tid - 8)], gss[tid - 8]);
}

// K9: GroupNorm + PReLU + alpha * gr + motion -> out
__global__ __launch_bounds__(256) void k9_out(
    const float* __restrict__ res, const float* __restrict__ gn,
    const void* __restrict__ mot,
    const void* __restrict__ gnw, const void* __restrict__ gnb,
    const void* __restrict__ pa, const void* __restrict__ al,
    const float* __restrict__ flag, void* __restrict__ out) {
  const bool f32 = flag[0] > 0.5f;
  const int idx = blockIdx.x * 256 + threadIdx.x;   // (b,c,n)
  const int n = idx & 4095;
  const int c = (idx >> 12) & 63;
  const int b = idx >> 18;
  const int g = c >> 3;
  const float inv_cnt = 1.f / 32768.f;
  float mean = gn[b * 8 + g] * inv_cnt;
  float var = gn[16 + b * 8 + g] * inv_cnt - mean * mean;
  var = fmaxf(var, 0.f);
  float rstd = rsqrtf(var + 1e-5f);
  float r = res[((size_t)b * NN + n) * 64 + c];
  float y = (r - mean) * rstd * ldin(gnw, c, f32) + ldin(gnb, c, f32);
  float slope = ldin(pa, 0, f32);
  y = (y >= 0.f) ? y : slope * y;
  float o = ldin(al, 0, f32) * y + ldin(mot, idx, f32);
  if (f32) ((float*)out)[idx] = o;
  else     ((__hip_bfloat16*)out)[idx] = __float2bfloat16(o);
}

extern "C" void kernel_launch(void* const* d_in, const int* in_sizes, int n_in,
                              void* d_out, int out_size, void* d_ws, size_t ws_size,
                              hipStream_t stream) {
  const void* ctx = d_in[0];
  const void* mot = d_in[1];
  const void* xyz = d_in[2];
  const void* wqk = d_in[3];
  const void* wv  = d_in[4];
  const void* bv  = d_in[5];
  const void* wt  = d_in[6];
  const void* bt  = d_in[7];
  const void* gnw = d_in[8];
  const void* gnb = d_in[9];
  const void* pa  = d_in[10];
  const void* al  = d_in[11];
  float* ws = (float*)d_ws;

  if (ws_size < (size_t)WS_TOTAL * sizeof(float))
    fprintf(stderr, "[gma3d] WARNING ws_size=%zu < needed %zu\n",
            ws_size, (size_t)WS_TOTAL * sizeof(float));

  hipMemsetAsync(ws + OFF_SUMS, 0, (size_t)ZERO_F * sizeof(float), stream);

  k0_detect<<<1, 256, 0, stream>>>((const unsigned short*)ctx, ws + OFF_FLAG);
  k1_q_xyz<<<32, 256, 0, stream>>>(ctx, xyz, wqk, ws + OFF_FLAG,
                                   ws + OFF_QT, ws + OFF_XYZ4, ws + OFF_SUMS);
  k2_xv<<<128, 256, 0, stream>>>(mot, wv, bv, ws + OFF_FLAG,
                                 (unsigned short*)(ws + OFF_XVB));
  k2b_thr<<<32, 256, 0, stream>>>(ws + OFF_XYZ4, ws + OFF_SUMS, ws + OFF_THR);
  p1_rs1<<<1024, 256, 0, stream>>>(ws + OFF_QT, ws + OFF_IRS1);
  p2_cs1<<<1024, 256, 0, stream>>>(ws + OFF_QT, ws + OFF_IRS1, ws + OFF_CS1);
  p3_rs2<<<2048, 256, 0, stream>>>(ws + OFF_QT, ws + OFF_XYZ4,
                                   ws + OFF_IRS1, ws + OFF_CS1, ws + OFF_THR,
                                   ws + OFF_IRS2);
  p4_cs2<<<2048, 256, 0, stream>>>(ws + OFF_QT, ws + OFF_XYZ4,
                                   ws + OFF_IRS1, ws + OFF_IRS2,
                                   ws + OFF_CS1, ws + OFF_THR, ws + OFF_CS2);
  k7_gma<<<1024, 256, 0, stream>>>(ws + OFF_QT, ws + OFF_XYZ4,
                                   (const unsigned short*)(ws + OFF_XVB),
                                   ws + OFF_IRS1, ws + OFF_IRS2,
                                   ws + OFF_CS1, ws + OFF_CS2, ws + OFF_THR,
                                   ws + OFF_GMA);
  k8_res<<<1024, 256, 0, stream>>>(mot, wt, bt, ws + OFF_FLAG, ws + OFF_GMA, ws + OFF_GN);
  k9_out<<<2048, 256, 0, stream>>>(ws + OFF_GMA, ws + OFF_GN, mot, gnw, gnb, pa, al,
                                   ws + OFF_FLAG, d_out);
}

// Round 5
// 527.930 us; speedup vs baseline: 1.3301x; 1.0058x over previous
//
#include <hip/hip_runtime.h>
#include <hip/hip_bf16.h>
#include <cstdio>

#define NB 2
#define NN 4096
#define NC 64
#define NQ 16
#define POS_COEF 0.1f

// ---- workspace layout (float offsets) ----
#define OFF_QT   0u            // [B][N][16]
#define OFF_XYZ4 131072u       // [B][N][4]
#define OFF_IRS1 163840u       // [B][N]
#define OFF_IRS2 172032u       // [B][N]
#define OFF_THR  180224u       // [B][N]
#define OFF_CS1  188416u       // [B][N] (written whole by p2, no zero)
#define OFF_CS2  196608u       // [B][N] (written whole by p4, no zero)
#define OFF_FLAG 204800u       // [16]
#define OFF_XVB  204816u       // [B][64][N] bf16 (262144 floats of space)
// --- zeroed region below ---
#define OFF_SUMS 466960u       // [B][4] {Px,Py,Pz,S1}
#define OFF_GN   466968u       // [2][B][8]
#define OFF_GMA  467000u       // [B][N][64] gma acc -> res in k8
#define WS_TOTAL 991288u
#define ZERO_F   (WS_TOTAL - OFF_SUMS)

using bf16x8 = __attribute__((ext_vector_type(8))) short;
using f32x4v = __attribute__((ext_vector_type(4))) float;

__device__ __forceinline__ float rcpf_(float x) { return __builtin_amdgcn_rcpf(x); }
__device__ __forceinline__ unsigned short f2bf(float x) {
  __hip_bfloat16 h = __float2bfloat16(x);
  return *(unsigned short*)&h;
}

// dtype-agnostic input load (flag is wave-uniform)
__device__ __forceinline__ float ldin(const void* p, size_t i, bool f32) {
  return f32 ? ((const float*)p)[i]
             : __bfloat162float(((const __hip_bfloat16*)p)[i]);
}

// 16-term fma tree over named float4s. NO ARRAYS -> no SROA/scratch trap.
#define DOT16M(A0,A1,A2,A3,B0,B1,B2,B3) \
  fmaf((A0).x,(B0).x, fmaf((A0).y,(B0).y, fmaf((A0).z,(B0).z, fmaf((A0).w,(B0).w, \
  fmaf((A1).x,(B1).x, fmaf((A1).y,(B1).y, fmaf((A1).z,(B1).z, fmaf((A1).w,(B1).w, \
  fmaf((A2).x,(B2).x, fmaf((A2).y,(B2).y, fmaf((A2).z,(B2).z, fmaf((A2).w,(B2).w, \
  fmaf((A3).x,(B3).x, fmaf((A3).y,(B3).y, fmaf((A3).z,(B3).z, (A3).w*(B3).w)))))))))))))))

// wave (64-lane) sum reduction on a named scalar
#define WRED(s) { s += __shfl_xor(s, 32); s += __shfl_xor(s, 16); \
  s += __shfl_xor(s, 8); s += __shfl_xor(s, 4); s += __shfl_xor(s, 2); s += __shfl_xor(s, 1); }

// named load of a 16-float q row
#define LQROW(v, base) \
  const float4 v##0 = *(const float4*)((base)); \
  const float4 v##1 = *(const float4*)((base) + 4); \
  const float4 v##2 = *(const float4*)((base) + 8); \
  const float4 v##3 = *(const float4*)((base) + 12);

// K0: detect input dtype (f32 misread as bf16 -> implausible exponents)
__global__ __launch_bounds__(256) void k0_detect(
    const unsigned short* __restrict__ ctx_u16, float* __restrict__ flag) {
  const int tid = threadIdx.x;
  int bad = 0;
  for (int i = tid; i < 8192; i += 256) {
    const unsigned short u = ctx_u16[i];
    const int e = (u >> 7) & 0xFF;
    if (e >= 134 || (e >= 1 && e <= 100)) bad++;
  }
  __shared__ int cnt;
  if (tid == 0) cnt = 0;
  __syncthreads();
  atomicAdd(&cnt, bad);
  __syncthreads();
  if (tid == 0) flag[0] = (cnt > 256) ? 1.0f : 0.0f;
}

// K1: q = Wqk @ ctx, xyz4 = {x,y,z,|p|^2}, batch sums {Px,Py,Pz,S1}
__global__ __launch_bounds__(256) void k1_q_xyz(
    const void* __restrict__ ctx, const void* __restrict__ xyz,
    const void* __restrict__ wqk, const float* __restrict__ flag,
    float* __restrict__ qt, float* __restrict__ xyz4, float* __restrict__ sums) {
  const bool f32 = flag[0] > 0.5f;
  const int tid = threadIdx.x;
  const int b = blockIdx.x >> 4;
  const int n = ((blockIdx.x & 15) << 8) + tid;
  __shared__ float wqT[NQ * NC];  // [c][o]
  for (int i = tid; i < NQ * NC; i += 256) {
    int o = i & 15, c = i >> 4;
    wqT[c * 16 + o] = ldin(wqk, o * 64 + c, f32);
  }
  __syncthreads();
  float4 a0 = {0,0,0,0}, a1 = {0,0,0,0}, a2 = {0,0,0,0}, a3 = {0,0,0,0};
  const size_t cbase = (size_t)b * 64 * NN + n;
#pragma unroll 4
  for (int c = 0; c < 64; ++c) {
    float x = ldin(ctx, cbase + (size_t)c * NN, f32);
    const float4 w0 = *(const float4*)(wqT + c * 16 + 0);
    const float4 w1 = *(const float4*)(wqT + c * 16 + 4);
    const float4 w2 = *(const float4*)(wqT + c * 16 + 8);
    const float4 w3 = *(const float4*)(wqT + c * 16 + 12);
    a0.x = fmaf(w0.x, x, a0.x); a0.y = fmaf(w0.y, x, a0.y); a0.z = fmaf(w0.z, x, a0.z); a0.w = fmaf(w0.w, x, a0.w);
    a1.x = fmaf(w1.x, x, a1.x); a1.y = fmaf(w1.y, x, a1.y); a1.z = fmaf(w1.z, x, a1.z); a1.w = fmaf(w1.w, x, a1.w);
    a2.x = fmaf(w2.x, x, a2.x); a2.y = fmaf(w2.y, x, a2.y); a2.z = fmaf(w2.z, x, a2.z); a2.w = fmaf(w2.w, x, a2.w);
    a3.x = fmaf(w3.x, x, a3.x); a3.y = fmaf(w3.y, x, a3.y); a3.z = fmaf(w3.z, x, a3.z); a3.w = fmaf(w3.w, x, a3.w);
  }
  float* qp = qt + (size_t)(b * NN + n) * 16;
  *(float4*)(qp + 0) = a0; *(float4*)(qp + 4) = a1;
  *(float4*)(qp + 8) = a2; *(float4*)(qp + 12) = a3;
  float xx = ldin(xyz, (size_t)(b * NN + n) * 3 + 0, f32);
  float yy = ldin(xyz, (size_t)(b * NN + n) * 3 + 1, f32);
  float zz = ldin(xyz, (size_t)(b * NN + n) * 3 + 2, f32);
  float4 p; p.x = xx; p.y = yy; p.z = zz; p.w = fmaf(xx, xx, fmaf(yy, yy, zz * zz));
  *(float4*)(xyz4 + (size_t)(b * NN + n) * 4) = p;
  float sx = p.x, sy = p.y, sz = p.z, sw = p.w;
  WRED(sx) WRED(sy) WRED(sz) WRED(sw)
  if ((tid & 63) == 0) {
    atomicAdd(&sums[b * 4 + 0], sx);
    atomicAdd(&sums[b * 4 + 1], sy);
    atomicAdd(&sums[b * 4 + 2], sz);
    atomicAdd(&sums[b * 4 + 3], sw);
  }
}

// K2: xv = Wv @ motion + bv, stored bf16 CHANNEL-MAJOR [b][c][n] for k7 B-operand
__global__ __launch_bounds__(256) void k2_xv(
    const void* __restrict__ mot, const void* __restrict__ wv,
    const void* __restrict__ bv, const float* __restrict__ flag,
    unsigned short* __restrict__ xvb) {
  const bool f32 = flag[0] > 0.5f;
  const int tid = threadIdx.x;
  const int b = blockIdx.x >> 6;
  const int n = ((blockIdx.x & 63) << 6) + (tid >> 2);
  const int og = tid & 3;
  __shared__ float wvT[NC * NC];
  __shared__ float bvs[NC];
  for (int i = tid; i < NC * NC; i += 256) {
    int o = i & 63, c = i >> 6;
    wvT[c * 64 + o] = ldin(wv, o * 64 + c, f32);
  }
  if (tid < 64) bvs[tid] = ldin(bv, tid, f32);
  __syncthreads();
  float4 a0 = *(const float4*)(bvs + og * 16 + 0);
  float4 a1 = *(const float4*)(bvs + og * 16 + 4);
  float4 a2 = *(const float4*)(bvs + og * 16 + 8);
  float4 a3 = *(const float4*)(bvs + og * 16 + 12);
  const size_t mbase = (size_t)b * 64 * NN + n;
#pragma unroll 4
  for (int c = 0; c < 64; ++c) {
    float x = ldin(mot, mbase + (size_t)c * NN, f32);
    const float4 w0 = *(const float4*)(wvT + c * 64 + og * 16 + 0);
    const float4 w1 = *(const float4*)(wvT + c * 64 + og * 16 + 4);
    const float4 w2 = *(const float4*)(wvT + c * 64 + og * 16 + 8);
    const float4 w3 = *(const float4*)(wvT + c * 64 + og * 16 + 12);
    a0.x = fmaf(w0.x, x, a0.x); a0.y = fmaf(w0.y, x, a0.y); a0.z = fmaf(w0.z, x, a0.z); a0.w = fmaf(w0.w, x, a0.w);
    a1.x = fmaf(w1.x, x, a1.x); a1.y = fmaf(w1.y, x, a1.y); a1.z = fmaf(w1.z, x, a1.z); a1.w = fmaf(w1.w, x, a1.w);
    a2.x = fmaf(w2.x, x, a2.x); a2.y = fmaf(w2.y, x, a2.y); a2.z = fmaf(w2.z, x, a2.z); a2.w = fmaf(w2.w, x, a2.w);
    a3.x = fmaf(w3.x, x, a3.x); a3.y = fmaf(w3.y, x, a3.y); a3.z = fmaf(w3.z, x, a3.z); a3.w = fmaf(w3.w, x, a3.w);
  }
  unsigned short* xb = xvb + (size_t)b * 64 * NN + n;
  const int o0 = og * 16;
  xb[(size_t)(o0 + 0) * NN] = f2bf(a0.x);  xb[(size_t)(o0 + 1) * NN] = f2bf(a0.y);
  xb[(size_t)(o0 + 2) * NN] = f2bf(a0.z);  xb[(size_t)(o0 + 3) * NN] = f2bf(a0.w);
  xb[(size_t)(o0 + 4) * NN] = f2bf(a1.x);  xb[(size_t)(o0 + 5) * NN] = f2bf(a1.y);
  xb[(size_t)(o0 + 6) * NN] = f2bf(a1.z);  xb[(size_t)(o0 + 7) * NN] = f2bf(a1.w);
  xb[(size_t)(o0 + 8) * NN] = f2bf(a2.x);  xb[(size_t)(o0 + 9) * NN] = f2bf(a2.y);
  xb[(size_t)(o0 +10) * NN] = f2bf(a2.z);  xb[(size_t)(o0 +11) * NN] = f2bf(a2.w);
  xb[(size_t)(o0 +12) * NN] = f2bf(a3.x);  xb[(size_t)(o0 +13) * NN] = f2bf(a3.y);
  xb[(size_t)(o0 +14) * NN] = f2bf(a3.z);  xb[(size_t)(o0 +15) * NN] = f2bf(a3.w);
}

// K2b: thr[n] = 0.1*(1e-9 + csd[n]), csd analytic
__global__ __launch_bounds__(256) void k2b_thr(
    const float* __restrict__ xyz4, const float* __restrict__ sums,
    float* __restrict__ thr) {
  const int idx = blockIdx.x * 256 + threadIdx.x;   // 8192
  const int b = idx >> 12;
  const float4 pn = *(const float4*)(xyz4 + (size_t)idx * 4);
  const float Px = sums[b * 4 + 0], Py = sums[b * 4 + 1];
  const float Pz = sums[b * 4 + 2], S1 = sums[b * 4 + 3];
  float csd = fmaf((float)NN, pn.w, S1)
            - 2.f * (pn.x * Px + pn.y * Py + pn.z * Pz);
  thr[idx] = POS_COEF * (1e-9f + csd);
}

// P1: irs1[m] = 1/sum_n exp(corr_mn). 8 rows/block, all state in NAMED regs.
__global__ __launch_bounds__(256) void p1_rs1(
    const float* __restrict__ qt, float* __restrict__ irs1) {
  const int tid = threadIdx.x;
  const int b = blockIdx.x >> 9;
  const int m0 = (blockIdx.x & 511) << 3;
  const float* qb = qt + (size_t)b * NN * 16;
  LQROW(ma, qb + (size_t)(m0 + 0) * 16)
  LQROW(mb, qb + (size_t)(m0 + 1) * 16)
  LQROW(mc, qb + (size_t)(m0 + 2) * 16)
  LQROW(md, qb + (size_t)(m0 + 3) * 16)
  LQROW(me, qb + (size_t)(m0 + 4) * 16)
  LQROW(mf, qb + (size_t)(m0 + 5) * 16)
  LQROW(mg, qb + (size_t)(m0 + 6) * 16)
  LQROW(mh, qb + (size_t)(m0 + 7) * 16)
  float s0 = 0.f, s1 = 0.f, s2 = 0.f, s3 = 0.f, s4 = 0.f, s5 = 0.f, s6 = 0.f, s7 = 0.f;
  for (int chunk = 0; chunk < 16; ++chunk) {
    const float* qn = qb + (size_t)((chunk << 8) + tid) * 16;
    LQROW(q, qn)
    s0 += __expf(fminf(DOT16M(q0, q1, q2, q3, ma0, ma1, ma2, ma3), 80.f));
    s1 += __expf(fminf(DOT16M(q0, q1, q2, q3, mb0, mb1, mb2, mb3), 80.f));
    s2 += __expf(fminf(DOT16M(q0, q1, q2, q3, mc0, mc1, mc2, mc3), 80.f));
    s3 += __expf(fminf(DOT16M(q0, q1, q2, q3, md0, md1, md2, md3), 80.f));
    s4 += __expf(fminf(DOT16M(q0, q1, q2, q3, me0, me1, me2, me3), 80.f));
    s5 += __expf(fminf(DOT16M(q0, q1, q2, q3, mf0, mf1, mf2, mf3), 80.f));
    s6 += __expf(fminf(DOT16M(q0, q1, q2, q3, mg0, mg1, mg2, mg3), 80.f));
    s7 += __expf(fminf(DOT16M(q0, q1, q2, q3, mh0, mh1, mh2, mh3), 80.f));
  }
  __shared__ float red[8][4];
  const int lane = tid & 63, wid = tid >> 6;
  WRED(s0) WRED(s1) WRED(s2) WRED(s3) WRED(s4) WRED(s5) WRED(s6) WRED(s7)
  if (lane == 0) {
    red[0][wid] = s0; red[1][wid] = s1; red[2][wid] = s2; red[3][wid] = s3;
    red[4][wid] = s4; red[5][wid] = s5; red[6][wid] = s6; red[7][wid] = s7;
  }
  __syncthreads();
  if (tid < 8)
    irs1[b * NN + m0 + tid] = rcpf_(red[tid][0] + red[tid][1] + red[tid][2] + red[tid][3]);
}

// P2: cs1[n] = sum_m exp(corr)*irs1[m]. 8 cols/block, named regs, no atomics.
__global__ __launch_bounds__(256) void p2_cs1(
    const float* __restrict__ qt, const float* __restrict__ irs1,
    float* __restrict__ cs1) {
  const int tid = threadIdx.x;
  const int b = blockIdx.x >> 9;
  const int n0 = (blockIdx.x & 511) << 3;
  const float* qb = qt + (size_t)b * NN * 16;
  LQROW(na, qb + (size_t)(n0 + 0) * 16)
  LQROW(nb, qb + (size_t)(n0 + 1) * 16)
  LQROW(nc, qb + (size_t)(n0 + 2) * 16)
  LQROW(nd, qb + (size_t)(n0 + 3) * 16)
  LQROW(ne, qb + (size_t)(n0 + 4) * 16)
  LQROW(nf, qb + (size_t)(n0 + 5) * 16)
  LQROW(ng, qb + (size_t)(n0 + 6) * 16)
  LQROW(nh, qb + (size_t)(n0 + 7) * 16)
  float s0 = 0.f, s1 = 0.f, s2 = 0.f, s3 = 0.f, s4 = 0.f, s5 = 0.f, s6 = 0.f, s7 = 0.f;
  for (int chunk = 0; chunk < 16; ++chunk) {
    const int m = (chunk << 8) + tid;
    const float* qm = qb + (size_t)m * 16;
    LQROW(f, qm)
    const float r1 = irs1[b * NN + m];
    s0 = fmaf(__expf(fminf(DOT16M(f0, f1, f2, f3, na0, na1, na2, na3), 80.f)), r1, s0);
    s1 = fmaf(__expf(fminf(DOT16M(f0, f1, f2, f3, nb0, nb1, nb2, nb3), 80.f)), r1, s1);
    s2 = fmaf(__expf(fminf(DOT16M(f0, f1, f2, f3, nc0, nc1, nc2, nc3), 80.f)), r1, s2);
    s3 = fmaf(__expf(fminf(DOT16M(f0, f1, f2, f3, nd0, nd1, nd2, nd3), 80.f)), r1, s3);
    s4 = fmaf(__expf(fminf(DOT16M(f0, f1, f2, f3, ne0, ne1, ne2, ne3), 80.f)), r1, s4);
    s5 = fmaf(__expf(fminf(DOT16M(f0, f1, f2, f3, nf0, nf1, nf2, nf3), 80.f)), r1, s5);
    s6 = fmaf(__expf(fminf(DOT16M(f0, f1, f2, f3, ng0, ng1, ng2, ng3), 80.f)), r1, s6);
    s7 = fmaf(__expf(fminf(DOT16M(f0, f1, f2, f3, nh0, nh1, nh2, nh3), 80.f)), r1, s7);
  }
  __shared__ float red[8][4];
  const int lane = tid & 63, wid = tid >> 6;
  WRED(s0) WRED(s1) WRED(s2) WRED(s3) WRED(s4) WRED(s5) WRED(s6) WRED(s7)
  if (lane == 0) {
    red[0][wid] = s0; red[1][wid] = s1; red[2][wid] = s2; red[3][wid] = s3;
    red[4][wid] = s4; red[5][wid] = s5; red[6][wid] = s6; red[7][wid] = s7;
  }
  __syncthreads();
  if (tid < 8)
    cs1[b * NN + n0 + tid] = red[tid][0] + red[tid][1] + red[tid][2] + red[tid][3];
}

// P3: irs2[m] = 1/sum_n exp(local0_mn). 4 rows/block, named regs.
__global__ __launch_bounds__(256) void p3_rs2(
    const float* __restrict__ qt, const float* __restrict__ xyz4,
    const float* __restrict__ irs1, const float* __restrict__ cs1,
    const float* __restrict__ thr, float* __restrict__ irs2) {
  const int tid = threadIdx.x;
  const int b = blockIdx.x >> 10;
  const int m0 = (blockIdx.x & 1023) << 2;
  const float* qb = qt + (size_t)b * NN * 16;
  const float* pb = xyz4 + (size_t)b * NN * 4;
  LQROW(ma, qb + (size_t)(m0 + 0) * 16)
  LQROW(mb, qb + (size_t)(m0 + 1) * 16)
  LQROW(mc, qb + (size_t)(m0 + 2) * 16)
  LQROW(md, qb + (size_t)(m0 + 3) * 16)
  const float4 pa = *(const float4*)(pb + (size_t)(m0 + 0) * 4);
  const float4 pc2 = *(const float4*)(pb + (size_t)(m0 + 1) * 4);
  const float4 pc3 = *(const float4*)(pb + (size_t)(m0 + 2) * 4);
  const float4 pc4 = *(const float4*)(pb + (size_t)(m0 + 3) * 4);
  const float ra = irs1[b * NN + m0 + 0];
  const float rb = irs1[b * NN + m0 + 1];
  const float rc = irs1[b * NN + m0 + 2];
  const float rd = irs1[b * NN + m0 + 3];
  float s0 = 0.f, s1 = 0.f, s2 = 0.f, s3 = 0.f;
#define P3ROW(Sx, M0,M1,M2,M3, PM, R1) { \
    float corr_ = DOT16M(q0, q1, q2, q3, M0, M1, M2, M3); \
    float a1v_ = __expf(fminf(corr_, 80.f)) * (R1) * ics1; \
    float dd_ = (PM).w + pn.w - 2.f * ((PM).x * pn.x + (PM).y * pn.y + (PM).z * pn.z); \
    dd_ = fmaxf(dd_, 0.f); \
    float l0_ = (dd_ <= thrn) ? a1v_ : 0.f; \
    Sx += __expf(l0_); }
  for (int chunk = 0; chunk < 16; ++chunk) {
    const int n = (chunk << 8) + tid;
    const float* qn = qb + (size_t)n * 16;
    LQROW(q, qn)
    const float4 pn = *(const float4*)(pb + (size_t)n * 4);
    const float ics1 = rcpf_(1e-9f + cs1[b * NN + n]);
    const float thrn = thr[b * NN + n];
    P3ROW(s0, ma0, ma1, ma2, ma3, pa, ra)
    P3ROW(s1, mb0, mb1, mb2, mb3, pc2, rb)
    P3ROW(s2, mc0, mc1, mc2, mc3, pc3, rc)
    P3ROW(s3, md0, md1, md2, md3, pc4, rd)
  }
#undef P3ROW
  __shared__ float red[4][4];
  const int lane = tid & 63, wid = tid >> 6;
  WRED(s0) WRED(s1) WRED(s2) WRED(s3)
  if (lane == 0) {
    red[0][wid] = s0; red[1][wid] = s1; red[2][wid] = s2; red[3][wid] = s3;
  }
  __syncthreads();
  if (tid < 4)
    irs2[b * NN + m0 + tid] = rcpf_(red[tid][0] + red[tid][1] + red[tid][2] + red[tid][3]);
}

// P4: cs2[n] = sum_m exp(local0)*irs2[m]. 4 cols/block, named regs.
__global__ __launch_bounds__(256) void p4_cs2(
    const float* __restrict__ qt, const float* __restrict__ xyz4,
    const float* __restrict__ irs1, const float* __restrict__ irs2,
    const float* __restrict__ cs1, const float* __restrict__ thr,
    float* __restrict__ cs2) {
  const int tid = threadIdx.x;
  const int b = blockIdx.x >> 10;
  const int n0 = (blockIdx.x & 1023) << 2;
  const float* qb = qt + (size_t)b * NN * 16;
  const float* pb = xyz4 + (size_t)b * NN * 4;
  LQROW(na, qb + (size_t)(n0 + 0) * 16)
  LQROW(nb, qb + (size_t)(n0 + 1) * 16)
  LQROW(nc, qb + (size_t)(n0 + 2) * 16)
  LQROW(nd, qb + (size_t)(n0 + 3) * 16)
  const float4 pna = *(const float4*)(pb + (size_t)(n0 + 0) * 4);
  const float4 pnb = *(const float4*)(pb + (size_t)(n0 + 1) * 4);
  const float4 pnc = *(const float4*)(pb + (size_t)(n0 + 2) * 4);
  const float4 pnd = *(const float4*)(pb + (size_t)(n0 + 3) * 4);
  const float ia = rcpf_(1e-9f + cs1[b * NN + n0 + 0]);
  const float ib = rcpf_(1e-9f + cs1[b * NN + n0 + 1]);
  const float ic = rcpf_(1e-9f + cs1[b * NN + n0 + 2]);
  const float id = rcpf_(1e-9f + cs1[b * NN + n0 + 3]);
  const float ta = thr[b * NN + n0 + 0];
  const float tb = thr[b * NN + n0 + 1];
  const float tc = thr[b * NN + n0 + 2];
  const float td = thr[b * NN + n0 + 3];
  float s0 = 0.f, s1 = 0.f, s2 = 0.f, s3 = 0.f;
#define P4COL(Sx, N0,N1,N2,N3, PN, ICS, THR) { \
    float corr_ = DOT16M(f0, f1, f2, f3, N0, N1, N2, N3); \
    float a1v_ = __expf(fminf(corr_, 80.f)) * r1 * (ICS); \
    float dd_ = pm.w + (PN).w - 2.f * (pm.x * (PN).x + pm.y * (PN).y + pm.z * (PN).z); \
    dd_ = fmaxf(dd_, 0.f); \
    float l0_ = (dd_ <= (THR)) ? a1v_ : 0.f; \
    Sx = fmaf(__expf(l0_), r2, Sx); }
  for (int chunk = 0; chunk < 16; ++chunk) {
    const int m = (chunk << 8) + tid;
    const float* qm = qb + (size_t)m * 16;
    LQROW(f, qm)
    const float4 pm = *(const float4*)(pb + (size_t)m * 4);
    const float r1 = irs1[b * NN + m];
    const float r2 = irs2[b * NN + m];
    P4COL(s0, na0, na1, na2, na3, pna, ia, ta)
    P4COL(s1, nb0, nb1, nb2, nb3, pnb, ib, tb)
    P4COL(s2, nc0, nc1, nc2, nc3, pnc, ic, tc)
    P4COL(s3, nd0, nd1, nd2, nd3, pnd, id, td)
  }
#undef P4COL
  __shared__ float red[4][4];
  const int lane = tid & 63, wid = tid >> 6;
  WRED(s0) WRED(s1) WRED(s2) WRED(s3)
  if (lane == 0) {
    red[0][wid] = s0; red[1][wid] = s1; red[2][wid] = s2; red[3][wid] = s3;
  }
  __syncthreads();
  if (tid < 4)
    cs2[b * NN + n0 + tid] = red[tid][0] + red[tid][1] + red[tid][2] + red[tid][3];
}

// K7: attn tile (phase A, f32 scalar) -> bf16 LDS -> MFMA with xv (phase B)
// grid 1024 = B * 64 n-tiles * 8 m-split; LDS 18.4 KB. Named MFMA accs.
__global__ __launch_bounds__(256) void k7_gma(
    const float* __restrict__ qt, const float* __restrict__ xyz4,
    const unsigned short* __restrict__ xvb,
    const float* __restrict__ irs1, const float* __restrict__ irs2,
    const float* __restrict__ cs1, const float* __restrict__ cs2,
    const float* __restrict__ thr, float* __restrict__ gma) {
  const int tid = threadIdx.x;
  const int bid = blockIdx.x;
  const int msl = bid & 7;
  const int nb = (bid >> 3) & 63;
  const int b = bid >> 9;
  const int n0 = nb << 6;
  const int mstart = msl << 9;
  __shared__ __align__(16) unsigned short attns[64 * 72];  // [n][m] A-layout
  __shared__ __align__(16) unsigned short xvs[64 * 72];    // [c][m] B-layout
  const float* qb = qt + (size_t)b * NN * 16;
  const float* pb = xyz4 + (size_t)b * NN * 4;
  const int ni = tid & 63, aw = tid >> 6;
  const int na = n0 + ni;
  const float* qnp = qb + (size_t)na * 16;
  LQROW(q, qnp)
  const float4 pn = *(const float4*)(pb + (size_t)na * 4);
  const float ics1 = rcpf_(1e-9f + cs1[b * NN + na]);
  const float ics2 = rcpf_(1e-9f + cs2[b * NN + na]);
  const float thr_n = thr[b * NN + na];
  const int lane = tid & 63, wv = tid >> 6;
  const int lr = lane & 15, quad = lane >> 4;
  const int nw = wv << 4;
  f32x4v acc0 = {0,0,0,0}, acc1 = {0,0,0,0}, acc2 = {0,0,0,0}, acc3 = {0,0,0,0};

  for (int mt = 0; mt < 8; ++mt) {
    const int m0 = mstart + (mt << 6);
    __syncthreads();
    {
      const int c = tid >> 2, part = tid & 3;
      const unsigned short* src = xvb + ((size_t)b * 64 + c) * NN + m0 + part * 16;
      unsigned short* dst = xvs + c * 72 + part * 16;
      *(uint4*)dst = *(const uint4*)src;
      *(uint4*)(dst + 8) = *(const uint4*)(src + 8);
    }
#pragma unroll
    for (int t = 0; t < 16; ++t) {
      const int m = __builtin_amdgcn_readfirstlane(m0 + aw + (t << 2));
      const float* qm = qb + (size_t)m * 16;
      LQROW(w, qm)
      float corr = DOT16M(q0, q1, q2, q3, w0, w1, w2, w3);
      const float4 pm = *(const float4*)(pb + (size_t)m * 4);
      float a1v = __expf(fminf(corr, 80.f)) * irs1[b * NN + m] * ics1;
      float dd = pm.w + pn.w - 2.f * (pm.x * pn.x + pm.y * pn.y + pm.z * pn.z);
      dd = fmaxf(dd, 0.f);
      float l0 = (dd <= thr_n) ? a1v : 0.f;
      float l2 = __expf(l0) * irs2[b * NN + m] * ics2;
      attns[ni * 72 + (m - m0)] = f2bf(a1v + l2);
    }
    __syncthreads();
#pragma unroll
    for (int h = 0; h < 2; ++h) {
      const bf16x8 a = *(const bf16x8*)(attns + (nw + lr) * 72 + h * 32 + quad * 8);
      const bf16x8 b0 = *(const bf16x8*)(xvs + (lr) * 72 + h * 32 + quad * 8);
      const bf16x8 b1 = *(const bf16x8*)(xvs + (16 + lr) * 72 + h * 32 + quad * 8);
      const bf16x8 b2 = *(const bf16x8*)(xvs + (32 + lr) * 72 + h * 32 + quad * 8);
      const bf16x8 b3 = *(const bf16x8*)(xvs + (48 + lr) * 72 + h * 32 + quad * 8);
      acc0 = __builtin_amdgcn_mfma_f32_16x16x32_bf16(a, b0, acc0, 0, 0, 0);
      acc1 = __builtin_amdgcn_mfma_f32_16x16x32_bf16(a, b1, acc1, 0, 0, 0);
      acc2 = __builtin_amdgcn_mfma_f32_16x16x32_bf16(a, b2, acc2, 0, 0, 0);
      acc3 = __builtin_amdgcn_mfma_f32_16x16x32_bf16(a, b3, acc3, 0, 0, 0);
    }
  }
  // epilogue: C-layout col=lane&15 (c), row=quad*4+reg (n)
#define EPI(ACC, CT) { \
    float* g_ = gma + ((size_t)b * NN + n0 + nw + (quad << 2)) * 64 + (CT) * 16 + lr; \
    atomicAdd(g_ + 0,   ACC[0]); \
    atomicAdd(g_ + 64,  ACC[1]); \
    atomicAdd(g_ + 128, ACC[2]); \
    atomicAdd(g_ + 192, ACC[3]); }
  EPI(acc0, 0) EPI(acc1, 1) EPI(acc2, 2) EPI(acc3, 3)
#undef EPI
}

// K8: res = Wt @ (motion - gma) + bt, in place over gma, + GroupNorm partials
__global__ __launch_bounds__(256) void k8_res(
    const void* __restrict__ mot, const void* __restrict__ wt,
    const void* __restrict__ bt, const float* __restrict__ flag,
    float* __restrict__ gma_res, float* __restrict__ gn) {
  const bool f32 = flag[0] > 0.5f;
  const int tid = threadIdx.x;
  const int bid = blockIdx.x;           // 1024 = B * 512
  const int b = bid >> 9;
  const int n0 = (bid & 511) << 3;
  __shared__ float wtT[64 * 65];
  __shared__ float bts[64];
  __shared__ float md[8 * 64];
  __shared__ float gs[8], gss[8];
  for (int i = tid; i < 4096; i += 256) {
    int o = i & 63, c = i >> 6;
    wtT[c * 65 + o] = ldin(wt, o * 64 + c, f32);
  }
  if (tid < 64) bts[tid] = ldin(bt, tid, f32);
  if (tid < 8) { gs[tid] = 0.f; gss[tid] = 0.f; }
#pragma unroll
  for (int r = 0; r < 2; ++r) {
    const int idx = tid * 2 + r;
    const int c = idx & 63, nl = idx >> 6;
    md[nl * 64 + c] = ldin(mot, ((size_t)b * 64 + c) * NN + n0 + nl, f32)
                    - gma_res[((size_t)b * NN + n0 + nl) * 64 + c];
  }
  __syncthreads();
  const int o = tid & 63, ng = tid >> 6;
  const int nl0 = ng * 2, nl1 = ng * 2 + 1;
  float a0 = bts[o], a1 = bts[o];
#pragma unroll 8
  for (int c = 0; c < 64; ++c) {
    float w = wtT[c * 65 + o];
    a0 = fmaf(w, md[nl0 * 64 + c], a0);
    a1 = fmaf(w, md[nl1 * 64 + c], a1);
  }
  gma_res[((size_t)b * NN + n0 + nl0) * 64 + o] = a0;
  gma_res[((size_t)b * NN + n0 + nl1) * 64 + o] = a1;
  atomicAdd(&gs[o >> 3], a0 + a1);
  atomicAdd(&gss[o >> 3], a0 * a0 + a1 * a1);
  __syncthreads();
  if (tid < 8) atomicAdd(&gn[b * 8 + tid], gs[tid]);
  else if (tid < 16) atomicAdd(&gn[16 + b * 8 + (tid - 8)], gss[tid - 8]);
}

// K9: GroupNorm + PReLU + alpha * gr + motion -> out
__global__ __launch_bounds__(256) void k9_out(
    const float* __restrict__ res, const float* __restrict__ gn,
    const void* __restrict__ mot,
    const void* __restrict__ gnw, const void* __restrict__ gnb,
    const void* __restrict__ pa, const void* __restrict__ al,
    const float* __restrict__ flag, void* __restrict__ out) {
  const bool f32 = flag[0] > 0.5f;
  const int idx = blockIdx.x * 256 + threadIdx.x;   // (b,c,n)
  const int n = idx & 4095;
  const int c = (idx >> 12) & 63;
  const int b = idx >> 18;
  const int g = c >> 3;
  const float inv_cnt = 1.f / 32768.f;
  float mean = gn[b * 8 + g] * inv_cnt;
  float var = gn[16 + b * 8 + g] * inv_cnt - mean * mean;
  var = fmaxf(var, 0.f);
  float rstd = rsqrtf(var + 1e-5f);
  float r = res[((size_t)b * NN + n) * 64 + c];
  float y = (r - mean) * rstd * ldin(gnw, c, f32) + ldin(gnb, c, f32);
  float slope = ldin(pa, 0, f32);
  y = (y >= 0.f) ? y : slope * y;
  float o = ldin(al, 0, f32) * y + ldin(mot, idx, f32);
  if (f32) ((float*)out)[idx] = o;
  else     ((__hip_bfloat16*)out)[idx] = __float2bfloat16(o);
}

extern "C" void kernel_launch(void* const* d_in, const int* in_sizes, int n_in,
                              void* d_out, int out_size, void* d_ws, size_t ws_size,
                              hipStream_t stream) {
  const void* ctx = d_in[0];
  const void* mot = d_in[1];
  const void* xyz = d_in[2];
  const void* wqk = d_in[3];
  const void* wv  = d_in[4];
  const void* bv  = d_in[5];
  const void* wt  = d_in[6];
  const void* bt  = d_in[7];
  const void* gnw = d_in[8];
  const void* gnb = d_in[9];
  const void* pa  = d_in[10];
  const void* al  = d_in[11];
  float* ws = (float*)d_ws;

  if (ws_size < (size_t)WS_TOTAL * sizeof(float))
    fprintf(stderr, "[gma3d] WARNING ws_size=%zu < needed %zu\n",
            ws_size, (size_t)WS_TOTAL * sizeof(float));

  hipMemsetAsync(ws + OFF_SUMS, 0, (size_t)ZERO_F * sizeof(float), stream);

  k0_detect<<<1, 256, 0, stream>>>((const unsigned short*)ctx, ws + OFF_FLAG);
  k1_q_xyz<<<32, 256, 0, stream>>>(ctx, xyz, wqk, ws + OFF_FLAG,
                                   ws + OFF_QT, ws + OFF_XYZ4, ws + OFF_SUMS);
  k2_xv<<<128, 256, 0, stream>>>(mot, wv, bv, ws + OFF_FLAG,
                                 (unsigned short*)(ws + OFF_XVB));
  k2b_thr<<<32, 256, 0, stream>>>(ws + OFF_XYZ4, ws + OFF_SUMS, ws + OFF_THR);
  p1_rs1<<<1024, 256, 0, stream>>>(ws + OFF_QT, ws + OFF_IRS1);
  p2_cs1<<<1024, 256, 0, stream>>>(ws + OFF_QT, ws + OFF_IRS1, ws + OFF_CS1);
  p3_rs2<<<2048, 256, 0, stream>>>(ws + OFF_QT, ws + OFF_XYZ4,
                                   ws + OFF_IRS1, ws + OFF_CS1, ws + OFF_THR,
                                   ws + OFF_IRS2);
  p4_cs2<<<2048, 256, 0, stream>>>(ws + OFF_QT, ws + OFF_XYZ4,
                                   ws + OFF_IRS1, ws + OFF_IRS2,
                                   ws + OFF_CS1, ws + OFF_THR, ws + OFF_CS2);
  k7_gma<<<1024, 256, 0, stream>>>(ws + OFF_QT, ws + OFF_XYZ4,
                                   (const unsigned short*)(ws + OFF_XVB),
                                   ws + OFF_IRS1, ws + OFF_IRS2,
                                   ws + OFF_CS1, ws + OFF_CS2, ws + OFF_THR,
                                   ws + OFF_GMA);
  k8_res<<<1024, 256, 0, stream>>>(mot, wt, bt, ws + OFF_FLAG, ws + OFF_GMA, ws + OFF_GN);
  k9_out<<<2048, 256, 0, stream>>>(ws + OFF_GMA, ws + OFF_GN, mot, gnw, gnb, pa, al,
                                   ws + OFF_FLAG, d_out);
}

// Round 6
// 381.683 us; speedup vs baseline: 1.8397x; 1.3832x over previous
//
#include <hip/hip_runtime.h>
#include <hip/hip_bf16.h>
#include <cstdio>

#define NB 2
#define NN 4096
#define NC 64
#define NQ 16
#define POS_COEF 0.1f

// ---- workspace layout (float offsets) ----
#define OFF_QT   0u            // [B][N][16] row-major q
#define OFF_QK   131072u       // [B][16][N] k-major q (coalesced stream side)
#define OFF_XYZ4 262144u       // [B][N][4]  row-major xyz+sq
#define OFF_XYZK 294912u       // [B][4][N]  plane-major xyz+sq
#define OFF_IRS1 327680u       // [B][N]
#define OFF_IRS2 335872u       // [B][N]
#define OFF_THR  344064u       // [B][N]
#define OFF_CS1  352256u       // [B][N]
#define OFF_CS2  360448u       // [B][N]
#define OFF_FLAG 368640u       // [16]
#define OFF_XVB  368656u       // [B][64][N] bf16 (262144 floats)
// --- zeroed region below ---
#define OFF_SUMS 630800u       // [B][4]
#define OFF_GN   630808u       // [2][B][8]
#define OFF_GMA  630840u       // [B][N][64]
#define WS_TOTAL 1155128u
#define ZERO_F   (WS_TOTAL - OFF_SUMS)

using bf16x8 = __attribute__((ext_vector_type(8))) short;
using f32x4v = __attribute__((ext_vector_type(4))) float;

__device__ __forceinline__ float rcpf_(float x) { return __builtin_amdgcn_rcpf(x); }
__device__ __forceinline__ unsigned short f2bf(float x) {
  __hip_bfloat16 h = __float2bfloat16(x);
  return *(unsigned short*)&h;
}

__device__ __forceinline__ float ldin(const void* p, size_t i, bool f32) {
  return f32 ? ((const float*)p)[i]
             : __bfloat162float(((const __hip_bfloat16*)p)[i]);
}

// 16-term fma tree, named float4 row against named float4 rows
#define DOT16M(A0,A1,A2,A3,B0,B1,B2,B3) \
  fmaf((A0).x,(B0).x, fmaf((A0).y,(B0).y, fmaf((A0).z,(B0).z, fmaf((A0).w,(B0).w, \
  fmaf((A1).x,(B1).x, fmaf((A1).y,(B1).y, fmaf((A1).z,(B1).z, fmaf((A1).w,(B1).w, \
  fmaf((A2).x,(B2).x, fmaf((A2).y,(B2).y, fmaf((A2).z,(B2).z, fmaf((A2).w,(B2).w, \
  fmaf((A3).x,(B3).x, fmaf((A3).y,(B3).y, fmaf((A3).z,(B3).z, (A3).w*(B3).w)))))))))))))))

// dot of named row (M0..M3) against column C of k-planes k0..k15
#define DOTC(M0,M1,M2,M3,C) \
  fmaf((M0).x,k0.C, fmaf((M0).y,k1.C, fmaf((M0).z,k2.C, fmaf((M0).w,k3.C, \
  fmaf((M1).x,k4.C, fmaf((M1).y,k5.C, fmaf((M1).z,k6.C, fmaf((M1).w,k7.C, \
  fmaf((M2).x,k8.C, fmaf((M2).y,k9.C, fmaf((M2).z,k10.C, fmaf((M2).w,k11.C, \
  fmaf((M3).x,k12.C, fmaf((M3).y,k13.C, fmaf((M3).z,k14.C, (M3).w*k15.C)))))))))))))))

// load 16 k-planes (4 consecutive n each) -- coalesced float4 loads
#define LKPL(base, n0) \
  const float4 k0  = *(const float4*)((base) + 0*NN  + (n0)); \
  const float4 k1  = *(const float4*)((base) + 1*NN  + (n0)); \
  const float4 k2  = *(const float4*)((base) + 2*NN  + (n0)); \
  const float4 k3  = *(const float4*)((base) + 3*NN  + (n0)); \
  const float4 k4  = *(const float4*)((base) + 4*NN  + (n0)); \
  const float4 k5  = *(const float4*)((base) + 5*NN  + (n0)); \
  const float4 k6  = *(const float4*)((base) + 6*NN  + (n0)); \
  const float4 k7  = *(const float4*)((base) + 7*NN  + (n0)); \
  const float4 k8  = *(const float4*)((base) + 8*NN  + (n0)); \
  const float4 k9  = *(const float4*)((base) + 9*NN  + (n0)); \
  const float4 k10 = *(const float4*)((base) + 10*NN + (n0)); \
  const float4 k11 = *(const float4*)((base) + 11*NN + (n0)); \
  const float4 k12 = *(const float4*)((base) + 12*NN + (n0)); \
  const float4 k13 = *(const float4*)((base) + 13*NN + (n0)); \
  const float4 k14 = *(const float4*)((base) + 14*NN + (n0)); \
  const float4 k15 = *(const float4*)((base) + 15*NN + (n0));

#define WRED(s) { s += __shfl_xor(s, 32); s += __shfl_xor(s, 16); \
  s += __shfl_xor(s, 8); s += __shfl_xor(s, 4); s += __shfl_xor(s, 2); s += __shfl_xor(s, 1); }

#define LQROW(v, base) \
  const float4 v##0 = *(const float4*)((base)); \
  const float4 v##1 = *(const float4*)((base) + 4); \
  const float4 v##2 = *(const float4*)((base) + 8); \
  const float4 v##3 = *(const float4*)((base) + 12);

// K0: detect input dtype
__global__ __launch_bounds__(256) void k0_detect(
    const unsigned short* __restrict__ ctx_u16, float* __restrict__ flag) {
  const int tid = threadIdx.x;
  int bad = 0;
  for (int i = tid; i < 8192; i += 256) {
    const unsigned short u = ctx_u16[i];
    const int e = (u >> 7) & 0xFF;
    if (e >= 134 || (e >= 1 && e <= 100)) bad++;
  }
  __shared__ int cnt;
  if (tid == 0) cnt = 0;
  __syncthreads();
  atomicAdd(&cnt, bad);
  __syncthreads();
  if (tid == 0) flag[0] = (cnt > 256) ? 1.0f : 0.0f;
}

// K1: q = Wqk @ ctx (row-major AND k-major), xyz4 + xyzk, batch sums
__global__ __launch_bounds__(256) void k1_q_xyz(
    const void* __restrict__ ctx, const void* __restrict__ xyz,
    const void* __restrict__ wqk, const float* __restrict__ flag,
    float* __restrict__ qt, float* __restrict__ qk,
    float* __restrict__ xyz4, float* __restrict__ xyzk,
    float* __restrict__ sums) {
  const bool f32 = flag[0] > 0.5f;
  const int tid = threadIdx.x;
  const int b = blockIdx.x >> 4;
  const int n = ((blockIdx.x & 15) << 8) + tid;
  __shared__ float wqT[NQ * NC];  // [c][o]
  for (int i = tid; i < NQ * NC; i += 256) {
    int o = i & 15, c = i >> 4;
    wqT[c * 16 + o] = ldin(wqk, o * 64 + c, f32);
  }
  __syncthreads();
  float4 a0 = {0,0,0,0}, a1 = {0,0,0,0}, a2 = {0,0,0,0}, a3 = {0,0,0,0};
  const size_t cbase = (size_t)b * 64 * NN + n;
#pragma unroll 4
  for (int c = 0; c < 64; ++c) {
    float x = ldin(ctx, cbase + (size_t)c * NN, f32);
    const float4 w0 = *(const float4*)(wqT + c * 16 + 0);
    const float4 w1 = *(const float4*)(wqT + c * 16 + 4);
    const float4 w2 = *(const float4*)(wqT + c * 16 + 8);
    const float4 w3 = *(const float4*)(wqT + c * 16 + 12);
    a0.x = fmaf(w0.x, x, a0.x); a0.y = fmaf(w0.y, x, a0.y); a0.z = fmaf(w0.z, x, a0.z); a0.w = fmaf(w0.w, x, a0.w);
    a1.x = fmaf(w1.x, x, a1.x); a1.y = fmaf(w1.y, x, a1.y); a1.z = fmaf(w1.z, x, a1.z); a1.w = fmaf(w1.w, x, a1.w);
    a2.x = fmaf(w2.x, x, a2.x); a2.y = fmaf(w2.y, x, a2.y); a2.z = fmaf(w2.z, x, a2.z); a2.w = fmaf(w2.w, x, a2.w);
    a3.x = fmaf(w3.x, x, a3.x); a3.y = fmaf(w3.y, x, a3.y); a3.z = fmaf(w3.z, x, a3.z); a3.w = fmaf(w3.w, x, a3.w);
  }
  float* qp = qt + (size_t)(b * NN + n) * 16;
  *(float4*)(qp + 0) = a0; *(float4*)(qp + 4) = a1;
  *(float4*)(qp + 8) = a2; *(float4*)(qp + 12) = a3;
  // k-major copy: for fixed k, lanes write consecutive n -> coalesced
  float* kq = qk + (size_t)b * 16 * NN + n;
  kq[0*NN]=a0.x;  kq[1*NN]=a0.y;  kq[2*NN]=a0.z;  kq[3*NN]=a0.w;
  kq[4*NN]=a1.x;  kq[5*NN]=a1.y;  kq[6*NN]=a1.z;  kq[7*NN]=a1.w;
  kq[8*NN]=a2.x;  kq[9*NN]=a2.y;  kq[10*NN]=a2.z; kq[11*NN]=a2.w;
  kq[12*NN]=a3.x; kq[13*NN]=a3.y; kq[14*NN]=a3.z; kq[15*NN]=a3.w;
  float xx = ldin(xyz, (size_t)(b * NN + n) * 3 + 0, f32);
  float yy = ldin(xyz, (size_t)(b * NN + n) * 3 + 1, f32);
  float zz = ldin(xyz, (size_t)(b * NN + n) * 3 + 2, f32);
  float4 p; p.x = xx; p.y = yy; p.z = zz; p.w = fmaf(xx, xx, fmaf(yy, yy, zz * zz));
  *(float4*)(xyz4 + (size_t)(b * NN + n) * 4) = p;
  float* kx = xyzk + (size_t)b * 4 * NN + n;
  kx[0*NN]=p.x; kx[1*NN]=p.y; kx[2*NN]=p.z; kx[3*NN]=p.w;
  float sx = p.x, sy = p.y, sz = p.z, sw = p.w;
  WRED(sx) WRED(sy) WRED(sz) WRED(sw)
  if ((tid & 63) == 0) {
    atomicAdd(&sums[b * 4 + 0], sx);
    atomicAdd(&sums[b * 4 + 1], sy);
    atomicAdd(&sums[b * 4 + 2], sz);
    atomicAdd(&sums[b * 4 + 3], sw);
  }
}

// K2: xv = Wv @ motion + bv, bf16 channel-major [b][c][n]
__global__ __launch_bounds__(256) void k2_xv(
    const void* __restrict__ mot, const void* __restrict__ wv,
    const void* __restrict__ bv, const float* __restrict__ flag,
    unsigned short* __restrict__ xvb) {
  const bool f32 = flag[0] > 0.5f;
  const int tid = threadIdx.x;
  const int b = blockIdx.x >> 6;
  const int n = ((blockIdx.x & 63) << 6) + (tid >> 2);
  const int og = tid & 3;
  __shared__ float wvT[NC * NC];
  __shared__ float bvs[NC];
  for (int i = tid; i < NC * NC; i += 256) {
    int o = i & 63, c = i >> 6;
    wvT[c * 64 + o] = ldin(wv, o * 64 + c, f32);
  }
  if (tid < 64) bvs[tid] = ldin(bv, tid, f32);
  __syncthreads();
  float4 a0 = *(const float4*)(bvs + og * 16 + 0);
  float4 a1 = *(const float4*)(bvs + og * 16 + 4);
  float4 a2 = *(const float4*)(bvs + og * 16 + 8);
  float4 a3 = *(const float4*)(bvs + og * 16 + 12);
  const size_t mbase = (size_t)b * 64 * NN + n;
#pragma unroll 4
  for (int c = 0; c < 64; ++c) {
    float x = ldin(mot, mbase + (size_t)c * NN, f32);
    const float4 w0 = *(const float4*)(wvT + c * 64 + og * 16 + 0);
    const float4 w1 = *(const float4*)(wvT + c * 64 + og * 16 + 4);
    const float4 w2 = *(const float4*)(wvT + c * 64 + og * 16 + 8);
    const float4 w3 = *(const float4*)(wvT + c * 64 + og * 16 + 12);
    a0.x = fmaf(w0.x, x, a0.x); a0.y = fmaf(w0.y, x, a0.y); a0.z = fmaf(w0.z, x, a0.z); a0.w = fmaf(w0.w, x, a0.w);
    a1.x = fmaf(w1.x, x, a1.x); a1.y = fmaf(w1.y, x, a1.y); a1.z = fmaf(w1.z, x, a1.z); a1.w = fmaf(w1.w, x, a1.w);
    a2.x = fmaf(w2.x, x, a2.x); a2.y = fmaf(w2.y, x, a2.y); a2.z = fmaf(w2.z, x, a2.z); a2.w = fmaf(w2.w, x, a2.w);
    a3.x = fmaf(w3.x, x, a3.x); a3.y = fmaf(w3.y, x, a3.y); a3.z = fmaf(w3.z, x, a3.z); a3.w = fmaf(w3.w, x, a3.w);
  }
  unsigned short* xb = xvb + (size_t)b * 64 * NN + n;
  const int o0 = og * 16;
  xb[(size_t)(o0 + 0) * NN] = f2bf(a0.x);  xb[(size_t)(o0 + 1) * NN] = f2bf(a0.y);
  xb[(size_t)(o0 + 2) * NN] = f2bf(a0.z);  xb[(size_t)(o0 + 3) * NN] = f2bf(a0.w);
  xb[(size_t)(o0 + 4) * NN] = f2bf(a1.x);  xb[(size_t)(o0 + 5) * NN] = f2bf(a1.y);
  xb[(size_t)(o0 + 6) * NN] = f2bf(a1.z);  xb[(size_t)(o0 + 7) * NN] = f2bf(a1.w);
  xb[(size_t)(o0 + 8) * NN] = f2bf(a2.x);  xb[(size_t)(o0 + 9) * NN] = f2bf(a2.y);
  xb[(size_t)(o0 +10) * NN] = f2bf(a2.z);  xb[(size_t)(o0 +11) * NN] = f2bf(a2.w);
  xb[(size_t)(o0 +12) * NN] = f2bf(a3.x);  xb[(size_t)(o0 +13) * NN] = f2bf(a3.y);
  xb[(size_t)(o0 +14) * NN] = f2bf(a3.z);  xb[(size_t)(o0 +15) * NN] = f2bf(a3.w);
}

// K2b: thr[n] = 0.1*(1e-9 + csd[n]) analytic
__global__ __launch_bounds__(256) void k2b_thr(
    const float* __restrict__ xyz4, const float* __restrict__ sums,
    float* __restrict__ thr) {
  const int idx = blockIdx.x * 256 + threadIdx.x;
  const int b = idx >> 12;
  const float4 pn = *(const float4*)(xyz4 + (size_t)idx * 4);
  const float Px = sums[b * 4 + 0], Py = sums[b * 4 + 1];
  const float Pz = sums[b * 4 + 2], S1 = sums[b * 4 + 3];
  float csd = fmaf((float)NN, pn.w, S1)
            - 2.f * (pn.x * Px + pn.y * Py + pn.z * Pz);
  thr[idx] = POS_COEF * (1e-9f + csd);
}

// P1: irs1[m] = 1/sum_n exp(corr). Wave owns 2 m-rows (32 hoisted floats);
// streams n via coalesced k-major float4 (4 cols/thread). No LDS, no atomics.
__global__ __launch_bounds__(256) void p1_rs1(
    const float* __restrict__ qt, const float* __restrict__ qk,
    float* __restrict__ irs1) {
  const int tid = threadIdx.x;
  const int b = blockIdx.x >> 9;                 // 1024 blocks
  const int m0 = (blockIdx.x & 511) << 3;        // 8 rows/block
  const int w = tid >> 6, lane = tid & 63;
  const float* qb = qt + (size_t)b * NN * 16;
  const float* kb = qk + (size_t)b * 16 * NN;
  const int mA = m0 + w, mB = m0 + w + 4;
  LQROW(ma, qb + (size_t)mA * 16)
  LQROW(mb, qb + (size_t)mB * 16)
  float sA = 0.f, sB = 0.f;
  for (int it = 0; it < 16; ++it) {
    const int n0 = (it << 8) + (lane << 2);
    LKPL(kb, n0)
    sA += __expf(fminf(DOTC(ma0,ma1,ma2,ma3,x), 80.f));
    sA += __expf(fminf(DOTC(ma0,ma1,ma2,ma3,y), 80.f));
    sA += __expf(fminf(DOTC(ma0,ma1,ma2,ma3,z), 80.f));
    sA += __expf(fminf(DOTC(ma0,ma1,ma2,ma3,w), 80.f));
    sB += __expf(fminf(DOTC(mb0,mb1,mb2,mb3,x), 80.f));
    sB += __expf(fminf(DOTC(mb0,mb1,mb2,mb3,y), 80.f));
    sB += __expf(fminf(DOTC(mb0,mb1,mb2,mb3,z), 80.f));
    sB += __expf(fminf(DOTC(mb0,mb1,mb2,mb3,w), 80.f));
  }
  WRED(sA) WRED(sB)
  if (lane == 0) {
    irs1[b * NN + mA] = rcpf_(sA);
    irs1[b * NN + mB] = rcpf_(sB);
  }
}

// P2: cs1[n] = sum_m exp(corr)*irs1[m]. Wave owns 2 n-rows; streams m coalesced.
__global__ __launch_bounds__(256) void p2_cs1(
    const float* __restrict__ qt, const float* __restrict__ qk,
    const float* __restrict__ irs1, float* __restrict__ cs1) {
  const int tid = threadIdx.x;
  const int b = blockIdx.x >> 9;
  const int n0t = (blockIdx.x & 511) << 3;
  const int w = tid >> 6, lane = tid & 63;
  const float* qb = qt + (size_t)b * NN * 16;
  const float* kb = qk + (size_t)b * 16 * NN;
  const int nA = n0t + w, nB = n0t + w + 4;
  LQROW(na, qb + (size_t)nA * 16)
  LQROW(nb, qb + (size_t)nB * 16)
  float sA = 0.f, sB = 0.f;
  for (int it = 0; it < 16; ++it) {
    const int m0 = (it << 8) + (lane << 2);
    LKPL(kb, m0)
    const float4 r1 = *(const float4*)(irs1 + b * NN + m0);
    sA = fmaf(__expf(fminf(DOTC(na0,na1,na2,na3,x), 80.f)), r1.x, sA);
    sA = fmaf(__expf(fminf(DOTC(na0,na1,na2,na3,y), 80.f)), r1.y, sA);
    sA = fmaf(__expf(fminf(DOTC(na0,na1,na2,na3,z), 80.f)), r1.z, sA);
    sA = fmaf(__expf(fminf(DOTC(na0,na1,na2,na3,w), 80.f)), r1.w, sA);
    sB = fmaf(__expf(fminf(DOTC(nb0,nb1,nb2,nb3,x), 80.f)), r1.x, sB);
    sB = fmaf(__expf(fminf(DOTC(nb0,nb1,nb2,nb3,y), 80.f)), r1.y, sB);
    sB = fmaf(__expf(fminf(DOTC(nb0,nb1,nb2,nb3,z), 80.f)), r1.z, sB);
    sB = fmaf(__expf(fminf(DOTC(nb0,nb1,nb2,nb3,w), 80.f)), r1.w, sB);
  }
  WRED(sA) WRED(sB)
  if (lane == 0) {
    cs1[b * NN + nA] = sA;
    cs1[b * NN + nB] = sB;
  }
}

// P3: irs2[m] = 1/sum_n exp(local0). Wave owns 2 m-rows; streams n coalesced.
__global__ __launch_bounds__(256) void p3_rs2(
    const float* __restrict__ qt, const float* __restrict__ qk,
    const float* __restrict__ xyz4, const float* __restrict__ xyzk,
    const float* __restrict__ irs1, const float* __restrict__ cs1,
    const float* __restrict__ thr, float* __restrict__ irs2) {
  const int tid = threadIdx.x;
  const int b = blockIdx.x >> 9;
  const int m0 = (blockIdx.x & 511) << 3;
  const int w = tid >> 6, lane = tid & 63;
  const float* qb = qt + (size_t)b * NN * 16;
  const float* kb = qk + (size_t)b * 16 * NN;
  const float* xk = xyzk + (size_t)b * 4 * NN;
  const int mA = m0 + w, mB = m0 + w + 4;
  LQROW(ma, qb + (size_t)mA * 16)
  LQROW(mb, qb + (size_t)mB * 16)
  const float4 pmA = *(const float4*)(xyz4 + ((size_t)b * NN + mA) * 4);
  const float4 pmB = *(const float4*)(xyz4 + ((size_t)b * NN + mB) * 4);
  const float rA = irs1[b * NN + mA];
  const float rB = irs1[b * NN + mB];
  float sA = 0.f, sB = 0.f;
#define P3C(S, M0,M1,M2,M3, PM, R, C, ICS) { \
    float corr_ = DOTC(M0,M1,M2,M3,C); \
    float a1v_ = __expf(fminf(corr_, 80.f)) * (R) * (ICS); \
    float dd_ = (PM).w + pw.C - 2.f * ((PM).x * px.C + (PM).y * py.C + (PM).z * pz.C); \
    dd_ = fmaxf(dd_, 0.f); \
    float l0_ = (dd_ <= th.C) ? a1v_ : 0.f; \
    S += __expf(l0_); }
  for (int it = 0; it < 16; ++it) {
    const int n0 = (it << 8) + (lane << 2);
    LKPL(kb, n0)
    const float4 px = *(const float4*)(xk + 0*NN + n0);
    const float4 py = *(const float4*)(xk + 1*NN + n0);
    const float4 pz = *(const float4*)(xk + 2*NN + n0);
    const float4 pw = *(const float4*)(xk + 3*NN + n0);
    const float4 c1 = *(const float4*)(cs1 + b * NN + n0);
    const float4 th = *(const float4*)(thr + b * NN + n0);
    const float ix = rcpf_(1e-9f + c1.x);
    const float iy = rcpf_(1e-9f + c1.y);
    const float iz = rcpf_(1e-9f + c1.z);
    const float iw = rcpf_(1e-9f + c1.w);
    P3C(sA, ma0,ma1,ma2,ma3, pmA, rA, x, ix)
    P3C(sA, ma0,ma1,ma2,ma3, pmA, rA, y, iy)
    P3C(sA, ma0,ma1,ma2,ma3, pmA, rA, z, iz)
    P3C(sA, ma0,ma1,ma2,ma3, pmA, rA, w, iw)
    P3C(sB, mb0,mb1,mb2,mb3, pmB, rB, x, ix)
    P3C(sB, mb0,mb1,mb2,mb3, pmB, rB, y, iy)
    P3C(sB, mb0,mb1,mb2,mb3, pmB, rB, z, iz)
    P3C(sB, mb0,mb1,mb2,mb3, pmB, rB, w, iw)
  }
#undef P3C
  WRED(sA) WRED(sB)
  if (lane == 0) {
    irs2[b * NN + mA] = rcpf_(sA);
    irs2[b * NN + mB] = rcpf_(sB);
  }
}

// P4: cs2[n] = sum_m exp(local0)*irs2[m]. Wave owns 2 n-rows; streams m coalesced.
__global__ __launch_bounds__(256) void p4_cs2(
    const float* __restrict__ qt, const float* __restrict__ qk,
    const float* __restrict__ xyz4, const float* __restrict__ xyzk,
    const float* __restrict__ irs1, const float* __restrict__ irs2,
    const float* __restrict__ cs1, const float* __restrict__ thr,
    float* __restrict__ cs2) {
  const int tid = threadIdx.x;
  const int b = blockIdx.x >> 9;
  const int n0t = (blockIdx.x & 511) << 3;
  const int w = tid >> 6, lane = tid & 63;
  const float* qb = qt + (size_t)b * NN * 16;
  const float* kb = qk + (size_t)b * 16 * NN;
  const float* xk = xyzk + (size_t)b * 4 * NN;
  const int nA = n0t + w, nB = n0t + w + 4;
  LQROW(na, qb + (size_t)nA * 16)
  LQROW(nb, qb + (size_t)nB * 16)
  const float4 pnA = *(const float4*)(xyz4 + ((size_t)b * NN + nA) * 4);
  const float4 pnB = *(const float4*)(xyz4 + ((size_t)b * NN + nB) * 4);
  const float iA = rcpf_(1e-9f + cs1[b * NN + nA]);
  const float iB = rcpf_(1e-9f + cs1[b * NN + nB]);
  const float tA = thr[b * NN + nA];
  const float tB = thr[b * NN + nB];
  float sA = 0.f, sB = 0.f;
#define P4C(S, N0,N1,N2,N3, PN, ICS, TH, C) { \
    float corr_ = DOTC(N0,N1,N2,N3,C); \
    float a1v_ = __expf(fminf(corr_, 80.f)) * r1.C * (ICS); \
    float dd_ = (PN).w + pw.C - 2.f * ((PN).x * px.C + (PN).y * py.C + (PN).z * pz.C); \
    dd_ = fmaxf(dd_, 0.f); \
    float l0_ = (dd_ <= (TH)) ? a1v_ : 0.f; \
    S = fmaf(__expf(l0_), r2.C, S); }
  for (int it = 0; it < 16; ++it) {
    const int m0 = (it << 8) + (lane << 2);
    LKPL(kb, m0)
    const float4 px = *(const float4*)(xk + 0*NN + m0);
    const float4 py = *(const float4*)(xk + 1*NN + m0);
    const float4 pz = *(const float4*)(xk + 2*NN + m0);
    const float4 pw = *(const float4*)(xk + 3*NN + m0);
    const float4 r1 = *(const float4*)(irs1 + b * NN + m0);
    const float4 r2 = *(const float4*)(irs2 + b * NN + m0);
    P4C(sA, na0,na1,na2,na3, pnA, iA, tA, x)
    P4C(sA, na0,na1,na2,na3, pnA, iA, tA, y)
    P4C(sA, na0,na1,na2,na3, pnA, iA, tA, z)
    P4C(sA, na0,na1,na2,na3, pnA, iA, tA, w)
    P4C(sB, nb0,nb1,nb2,nb3, pnB, iB, tB, x)
    P4C(sB, nb0,nb1,nb2,nb3, pnB, iB, tB, y)
    P4C(sB, nb0,nb1,nb2,nb3, pnB, iB, tB, z)
    P4C(sB, nb0,nb1,nb2,nb3, pnB, iB, tB, w)
  }
#undef P4C
  WRED(sA) WRED(sB)
  if (lane == 0) {
    cs2[b * NN + nA] = sA;
    cs2[b * NN + nB] = sB;
  }
}

// K7: attn tile (phase A scalar) -> bf16 LDS -> MFMA vs xv (phase B)
__global__ __launch_bounds__(256) void k7_gma(
    const float* __restrict__ qt, const float* __restrict__ xyz4,
    const unsigned short* __restrict__ xvb,
    const float* __restrict__ irs1, const float* __restrict__ irs2,
    const float* __restrict__ cs1, const float* __restrict__ cs2,
    const float* __restrict__ thr, float* __restrict__ gma) {
  const int tid = threadIdx.x;
  const int bid = blockIdx.x;
  const int msl = bid & 7;
  const int nb = (bid >> 3) & 63;
  const int b = bid >> 9;
  const int n0 = nb << 6;
  const int mstart = msl << 9;
  __shared__ __align__(16) unsigned short attns[64 * 72];
  __shared__ __align__(16) unsigned short xvs[64 * 72];
  const float* qb = qt + (size_t)b * NN * 16;
  const float* pb = xyz4 + (size_t)b * NN * 4;
  const int ni = tid & 63, aw = tid >> 6;
  const int na = n0 + ni;
  const float* qnp = qb + (size_t)na * 16;
  LQROW(q, qnp)
  const float4 pn = *(const float4*)(pb + (size_t)na * 4);
  const float ics1 = rcpf_(1e-9f + cs1[b * NN + na]);
  const float ics2 = rcpf_(1e-9f + cs2[b * NN + na]);
  const float thr_n = thr[b * NN + na];
  const int lane = tid & 63, wv = tid >> 6;
  const int lr = lane & 15, quad = lane >> 4;
  const int nw = wv << 4;
  f32x4v acc0 = {0,0,0,0}, acc1 = {0,0,0,0}, acc2 = {0,0,0,0}, acc3 = {0,0,0,0};

  for (int mt = 0; mt < 8; ++mt) {
    const int m0 = mstart + (mt << 6);
    __syncthreads();
    {
      const int c = tid >> 2, part = tid & 3;
      const unsigned short* src = xvb + ((size_t)b * 64 + c) * NN + m0 + part * 16;
      unsigned short* dst = xvs + c * 72 + part * 16;
      *(uint4*)dst = *(const uint4*)src;
      *(uint4*)(dst + 8) = *(const uint4*)(src + 8);
    }
#pragma unroll
    for (int t = 0; t < 16; ++t) {
      const int m = __builtin_amdgcn_readfirstlane(m0 + aw + (t << 2));
      const float* qm = qb + (size_t)m * 16;
      LQROW(w, qm)
      float corr = DOT16M(q0, q1, q2, q3, w0, w1, w2, w3);
      const float4 pm = *(const float4*)(pb + (size_t)m * 4);
      float a1v = __expf(fminf(corr, 80.f)) * irs1[b * NN + m] * ics1;
      float dd = pm.w + pn.w - 2.f * (pm.x * pn.x + pm.y * pn.y + pm.z * pn.z);
      dd = fmaxf(dd, 0.f);
      float l0 = (dd <= thr_n) ? a1v : 0.f;
      float l2 = __expf(l0) * irs2[b * NN + m] * ics2;
      attns[ni * 72 + (m - m0)] = f2bf(a1v + l2);
    }
    __syncthreads();
#pragma unroll
    for (int h = 0; h < 2; ++h) {
      const bf16x8 a = *(const bf16x8*)(attns + (nw + lr) * 72 + h * 32 + quad * 8);
      const bf16x8 b0 = *(const bf16x8*)(xvs + (lr) * 72 + h * 32 + quad * 8);
      const bf16x8 b1 = *(const bf16x8*)(xvs + (16 + lr) * 72 + h * 32 + quad * 8);
      const bf16x8 b2 = *(const bf16x8*)(xvs + (32 + lr) * 72 + h * 32 + quad * 8);
      const bf16x8 b3 = *(const bf16x8*)(xvs + (48 + lr) * 72 + h * 32 + quad * 8);
      acc0 = __builtin_amdgcn_mfma_f32_16x16x32_bf16(a, b0, acc0, 0, 0, 0);
      acc1 = __builtin_amdgcn_mfma_f32_16x16x32_bf16(a, b1, acc1, 0, 0, 0);
      acc2 = __builtin_amdgcn_mfma_f32_16x16x32_bf16(a, b2, acc2, 0, 0, 0);
      acc3 = __builtin_amdgcn_mfma_f32_16x16x32_bf16(a, b3, acc3, 0, 0, 0);
    }
  }
#define EPI(ACC, CT) { \
    float* g_ = gma + ((size_t)b * NN + n0 + nw + (quad << 2)) * 64 + (CT) * 16 + lr; \
    atomicAdd(g_ + 0,   ACC[0]); \
    atomicAdd(g_ + 64,  ACC[1]); \
    atomicAdd(g_ + 128, ACC[2]); \
    atomicAdd(g_ + 192, ACC[3]); }
  EPI(acc0, 0) EPI(acc1, 1) EPI(acc2, 2) EPI(acc3, 3)
#undef EPI
}

// K8: res = Wt @ (motion - gma) + bt, in place, + GroupNorm partials
__global__ __launch_bounds__(256) void k8_res(
    const void* __restrict__ mot, const void* __restrict__ wt,
    const void* __restrict__ bt, const float* __restrict__ flag,
    float* __restrict__ gma_res, float* __restrict__ gn) {
  const bool f32 = flag[0] > 0.5f;
  const int tid = threadIdx.x;
  const int bid = blockIdx.x;           // 1024 = B * 512
  const int b = bid >> 9;
  const int n0 = (bid & 511) << 3;
  __shared__ float wtT[64 * 65];
  __shared__ float bts[64];
  __shared__ float md[8 * 64];
  __shared__ float gs[8], gss[8];
  for (int i = tid; i < 4096; i += 256) {
    int o = i & 63, c = i >> 6;
    wtT[c * 65 + o] = ldin(wt, o * 64 + c, f32);
  }
  if (tid < 64) bts[tid] = ldin(bt, tid, f32);
  if (tid < 8) { gs[tid] = 0.f; gss[tid] = 0.f; }
#pragma unroll
  for (int r = 0; r < 2; ++r) {
    const int idx = tid * 2 + r;
    const int c = idx & 63, nl = idx >> 6;
    md[nl * 64 + c] = ldin(mot, ((size_t)b * 64 + c) * NN + n0 + nl, f32)
                    - gma_res[((size_t)b * NN + n0 + nl) * 64 + c];
  }
  __syncthreads();
  const int o = tid & 63, ng = tid >> 6;
  const int nl0 = ng * 2, nl1 = ng * 2 + 1;
  float a0 = bts[o], a1 = bts[o];
#pragma unroll 8
  for (int c = 0; c < 64; ++c) {
    float w = wtT[c * 65 + o];
    a0 = fmaf(w, md[nl0 * 64 + c], a0);
    a1 = fmaf(w, md[nl1 * 64 + c], a1);
  }
  gma_res[((size_t)b * NN + n0 + nl0) * 64 + o] = a0;
  gma_res[((size_t)b * NN + n0 + nl1) * 64 + o] = a1;
  atomicAdd(&gs[o >> 3], a0 + a1);
  atomicAdd(&gss[o >> 3], a0 * a0 + a1 * a1);
  __syncthreads();
  if (tid < 8) atomicAdd(&gn[b * 8 + tid], gs[tid]);
  else if (tid < 16) atomicAdd(&gn[16 + b * 8 + (tid - 8)], gss[tid - 8]);
}

// K9: GroupNorm + PReLU + alpha * gr + motion -> out
__global__ __launch_bounds__(256) void k9_out(
    const float* __restrict__ res, const float* __restrict__ gn,
    const void* __restrict__ mot,
    const void* __restrict__ gnw, const void* __restrict__ gnb,
    const void* __restrict__ pa, const void* __restrict__ al,
    const float* __restrict__ flag, void* __restrict__ out) {
  const bool f32 = flag[0] > 0.5f;
  const int idx = blockIdx.x * 256 + threadIdx.x;
  const int n = idx & 4095;
  const int c = (idx >> 12) & 63;
  const int b = idx >> 18;
  const int g = c >> 3;
  const float inv_cnt = 1.f / 32768.f;
  float mean = gn[b * 8 + g] * inv_cnt;
  float var = gn[16 + b * 8 + g] * inv_cnt - mean * mean;
  var = fmaxf(var, 0.f);
  float rstd = rsqrtf(var + 1e-5f);
  float r = res[((size_t)b * NN + n) * 64 + c];
  float y = (r - mean) * rstd * ldin(gnw, c, f32) + ldin(gnb, c, f32);
  float slope = ldin(pa, 0, f32);
  y = (y >= 0.f) ? y : slope * y;
  float o = ldin(al, 0, f32) * y + ldin(mot, idx, f32);
  if (f32) ((float*)out)[idx] = o;
  else     ((__hip_bfloat16*)out)[idx] = __float2bfloat16(o);
}

extern "C" void kernel_launch(void* const* d_in, const int* in_sizes, int n_in,
                              void* d_out, int out_size, void* d_ws, size_t ws_size,
                              hipStream_t stream) {
  const void* ctx = d_in[0];
  const void* mot = d_in[1];
  const void* xyz = d_in[2];
  const void* wqk = d_in[3];
  const void* wv  = d_in[4];
  const void* bv  = d_in[5];
  const void* wt  = d_in[6];
  const void* bt  = d_in[7];
  const void* gnw = d_in[8];
  const void* gnb = d_in[9];
  const void* pa  = d_in[10];
  const void* al  = d_in[11];
  float* ws = (float*)d_ws;

  if (ws_size < (size_t)WS_TOTAL * sizeof(float))
    fprintf(stderr, "[gma3d] WARNING ws_size=%zu < needed %zu\n",
            ws_size, (size_t)WS_TOTAL * sizeof(float));

  hipMemsetAsync(ws + OFF_SUMS, 0, (size_t)ZERO_F * sizeof(float), stream);

  k0_detect<<<1, 256, 0, stream>>>((const unsigned short*)ctx, ws + OFF_FLAG);
  k1_q_xyz<<<32, 256, 0, stream>>>(ctx, xyz, wqk, ws + OFF_FLAG,
                                   ws + OFF_QT, ws + OFF_QK,
                                   ws + OFF_XYZ4, ws + OFF_XYZK, ws + OFF_SUMS);
  k2_xv<<<128, 256, 0, stream>>>(mot, wv, bv, ws + OFF_FLAG,
                                 (unsigned short*)(ws + OFF_XVB));
  k2b_thr<<<32, 256, 0, stream>>>(ws + OFF_XYZ4, ws + OFF_SUMS, ws + OFF_THR);
  p1_rs1<<<1024, 256, 0, stream>>>(ws + OFF_QT, ws + OFF_QK, ws + OFF_IRS1);
  p2_cs1<<<1024, 256, 0, stream>>>(ws + OFF_QT, ws + OFF_QK, ws + OFF_IRS1, ws + OFF_CS1);
  p3_rs2<<<1024, 256, 0, stream>>>(ws + OFF_QT, ws + OFF_QK,
                                   ws + OFF_XYZ4, ws + OFF_XYZK,
                                   ws + OFF_IRS1, ws + OFF_CS1, ws + OFF_THR,
                                   ws + OFF_IRS2);
  p4_cs2<<<1024, 256, 0, stream>>>(ws + OFF_QT, ws + OFF_QK,
                                   ws + OFF_XYZ4, ws + OFF_XYZK,
                                   ws + OFF_IRS1, ws + OFF_IRS2,
                                   ws + OFF_CS1, ws + OFF_THR, ws + OFF_CS2);
  k7_gma<<<1024, 256, 0, stream>>>(ws + OFF_QT, ws + OFF_XYZ4,
                                   (const unsigned short*)(ws + OFF_XVB),
                                   ws + OFF_IRS1, ws + OFF_IRS2,
                                   ws + OFF_CS1, ws + OFF_CS2, ws + OFF_THR,
                                   ws + OFF_GMA);
  k8_res<<<1024, 256, 0, stream>>>(mot, wt, bt, ws + OFF_FLAG, ws + OFF_GMA, ws + OFF_GN);
  k9_out<<<2048, 256, 0, stream>>>(ws + OFF_GMA, ws + OFF_GN, mot, gnw, gnb, pa, al,
                                   ws + OFF_FLAG, d_out);
}